// Round 1
// baseline (169.124 us; speedup 1.0000x reference)
//
#include <hip/hip_runtime.h>

#define LSEQ 8192
#define NBAT 16
#define DMOD 16
#define DINN 32
#define DSTA 16
#define CL   128
#define NCH  (LSEQ / CL)          // 64
#define RECF 128                  // floats per row record
#define NROWS (NBAT * LSEQ)       // 131072
#define SUMN (NBAT * NCH * 512)   // chunk-summary elements

__device__ __forceinline__ float fsilu(float v) { return v / (1.f + __expf(-v)); }
__device__ __forceinline__ float fsoftplus(float v) {
  return v > 20.f ? v : __logf(1.f + __expf(v));
}

// Compute xm[32] (and z[32] if WANTZ) for global row r (r = b*LSEQ + l).
template <bool WANTZ>
__device__ __forceinline__ void row_inproj(const float* __restrict__ x,
                                           const float* __restrict__ rms1w,
                                           const float* __restrict__ ipw,
                                           long r, float* __restrict__ xm,
                                           float* __restrict__ z) {
  float xr[16];
  const float4* xp = reinterpret_cast<const float4*>(x + r * DMOD);
  float4 v0 = xp[0], v1 = xp[1], v2 = xp[2], v3 = xp[3];
  xr[0] = v0.x; xr[1] = v0.y; xr[2] = v0.z; xr[3] = v0.w;
  xr[4] = v1.x; xr[5] = v1.y; xr[6] = v1.z; xr[7] = v1.w;
  xr[8] = v2.x; xr[9] = v2.y; xr[10] = v2.z; xr[11] = v2.w;
  xr[12] = v3.x; xr[13] = v3.y; xr[14] = v3.z; xr[15] = v3.w;
  float ss = 0.f;
#pragma unroll
  for (int i = 0; i < 16; i++) ss += xr[i] * xr[i];
  float inv = rsqrtf(ss * (1.f / 16.f) + 1e-6f);
  float x0[16];
#pragma unroll
  for (int i = 0; i < 16; i++) x0[i] = xr[i] * inv * rms1w[i];
  if (WANTZ) {
    float acc[64];
#pragma unroll
    for (int k = 0; k < 64; k++) acc[k] = 0.f;
#pragma unroll
    for (int i = 0; i < 16; i++) {
      float xi = x0[i];
#pragma unroll
      for (int k = 0; k < 64; k++) acc[k] = fmaf(xi, ipw[i * 64 + k], acc[k]);
    }
#pragma unroll
    for (int k = 0; k < 32; k++) { xm[k] = acc[k]; z[k] = acc[32 + k]; }
  } else {
    float acc[32];
#pragma unroll
    for (int k = 0; k < 32; k++) acc[k] = 0.f;
#pragma unroll
    for (int i = 0; i < 16; i++) {
      float xi = x0[i];
#pragma unroll
      for (int k = 0; k < 32; k++) acc[k] = fmaf(xi, ipw[i * 64 + k], acc[k]);
    }
#pragma unroll
    for (int k = 0; k < 32; k++) xm[k] = acc[k];
  }
}

// K1: per-row prep.  Record layout (floats): [0:32)=dt [32:64)=xc [64:80)=Bv
// [80:96)=Cv [96:128)=z
__global__ __launch_bounds__(256) void k_prep(
    const float* __restrict__ x, const float* __restrict__ rms1w,
    const float* __restrict__ ipw, const float* __restrict__ cw,
    const float* __restrict__ cb, const float* __restrict__ xpw,
    const float* __restrict__ dtw, const float* __restrict__ dtb,
    float* __restrict__ rec) {
  __shared__ float xmv[256 + 3][DINN + 1];  // +1 pad: conv read bank spread
  int tid = threadIdx.x;
  long row0 = (long)blockIdx.x * 256;
  long r = row0 + tid;
  // halo rows (3 preceding rows of this block, xm only)
  if (tid < 3) {
    int l0 = (int)(row0 & (LSEQ - 1));
    int lh = l0 - 3 + tid;
    float xmh[32];
    if (lh < 0) {
#pragma unroll
      for (int d = 0; d < 32; d++) xmh[d] = 0.f;
    } else {
      row_inproj<false>(x, rms1w, ipw, row0 - 3 + tid, xmh, nullptr);
    }
#pragma unroll
    for (int d = 0; d < 32; d++) xmv[tid][d] = xmh[d];
  }
  float xm[32], zv[32];
  row_inproj<true>(x, rms1w, ipw, r, xm, zv);
#pragma unroll
  for (int d = 0; d < 32; d++) xmv[tid + 3][d] = xm[d];
  float* rrec = rec + (size_t)r * RECF;
#pragma unroll
  for (int d = 0; d < 32; d += 4) {
    float4 w = make_float4(zv[d], zv[d + 1], zv[d + 2], zv[d + 3]);
    *reinterpret_cast<float4*>(rrec + 96 + d) = w;
  }
  __syncthreads();
  // causal depthwise conv + silu
  float xc[32];
#pragma unroll
  for (int d = 0; d < 32; d++) {
    float c = cb[d];
#pragma unroll
    for (int k = 0; k < 4; k++) c = fmaf(cw[d * 4 + k], xmv[tid + k][d], c);
    xc[d] = fsilu(c);
  }
  // x_proj: proj[33] = xc @ xpw[32][33]
  float proj[33];
#pragma unroll
  for (int k = 0; k < 33; k++) proj[k] = 0.f;
#pragma unroll
  for (int d = 0; d < 32; d++) {
    float v = xc[d];
#pragma unroll
    for (int k = 0; k < 33; k++) proj[k] = fmaf(v, xpw[d * 33 + k], proj[k]);
  }
  float dtv[32];
#pragma unroll
  for (int d = 0; d < 32; d++) dtv[d] = fsoftplus(proj[0] * dtw[d] + dtb[d]);
#pragma unroll
  for (int d = 0; d < 32; d += 4) {
    *reinterpret_cast<float4*>(rrec + d) =
        make_float4(dtv[d], dtv[d + 1], dtv[d + 2], dtv[d + 3]);
    *reinterpret_cast<float4*>(rrec + 32 + d) =
        make_float4(xc[d], xc[d + 1], xc[d + 2], xc[d + 3]);
  }
#pragma unroll
  for (int k = 0; k < 16; k += 4) {
    *reinterpret_cast<float4*>(rrec + 64 + k) =
        make_float4(proj[1 + k], proj[2 + k], proj[3 + k], proj[4 + k]);
    *reinterpret_cast<float4*>(rrec + 80 + k) =
        make_float4(proj[17 + k], proj[18 + k], proj[19 + k], proj[20 + k]);
  }
}

// K2: per-chunk local scan -> P (decay product), H (state with h0=0)
__global__ __launch_bounds__(128) void k_chunk(const float* __restrict__ rec,
                                               const float* __restrict__ A_log,
                                               float* __restrict__ Pb,
                                               float* __restrict__ Hb) {
  int t = threadIdx.x;
  int s = t & 15, d0 = (t >> 4) * 4;
  int bc = blockIdx.x;
  const float* rbase = rec + (size_t)bc * CL * RECF;
  float Ad[4];
#pragma unroll
  for (int q = 0; q < 4; q++) Ad[q] = -__expf(A_log[(d0 + q) * DSTA + s]);
  float P[4] = {1.f, 1.f, 1.f, 1.f};
  float Hh[4] = {0.f, 0.f, 0.f, 0.f};
#pragma unroll 4
  for (int l = 0; l < CL; l++) {
    const float* rl = rbase + l * RECF;
    float4 dt4 = *reinterpret_cast<const float4*>(rl + d0);
    float4 xc4 = *reinterpret_cast<const float4*>(rl + 32 + d0);
    float bvs = rl[64 + s];
    float dts[4] = {dt4.x, dt4.y, dt4.z, dt4.w};
    float xcs[4] = {xc4.x, xc4.y, xc4.z, xc4.w};
#pragma unroll
    for (int q = 0; q < 4; q++) {
      float a = __expf(dts[q] * Ad[q]);
      Hh[q] = fmaf(a, Hh[q], dts[q] * bvs * xcs[q]);
      P[q] *= a;
    }
  }
  size_t base = (size_t)bc * 512 + t * 4;
  *reinterpret_cast<float4*>(Pb + base) = make_float4(P[0], P[1], P[2], P[3]);
  *reinterpret_cast<float4*>(Hb + base) = make_float4(Hh[0], Hh[1], Hh[2], Hh[3]);
}

// K3: exclusive scan over chunks (per batch, 512 independent states)
__global__ __launch_bounds__(512) void k_combine(const float* __restrict__ Pb,
                                                 const float* __restrict__ Hb,
                                                 float* __restrict__ hs) {
  int b = blockIdx.x, t = threadIdx.x;
  size_t base = (size_t)b * NCH * 512 + t;
  float h = 0.f;
#pragma unroll 8
  for (int c = 0; c < NCH; c++) {
    hs[base + (size_t)c * 512] = h;
    h = fmaf(Pb[base + (size_t)c * 512], h, Hb[base + (size_t)c * 512]);
  }
}

// K4: per-chunk scan with outputs + fused epilogue
__global__ __launch_bounds__(128) void k_out(
    const float* __restrict__ rec, const float* __restrict__ x,
    const float* __restrict__ A_log, const float* __restrict__ hs,
    const float* __restrict__ Dskip, const float* __restrict__ opw,
    const float* __restrict__ rms2w, const float* __restrict__ f1w,
    const float* __restrict__ f1b, const float* __restrict__ f2w,
    const float* __restrict__ f2b, const float* __restrict__ f3w,
    const float* __restrict__ f3b, float* __restrict__ out) {
  __shared__ float yv[CL][DINN + 1];  // stride 33: conflict-free column reads
  int t = threadIdx.x;
  int s = t & 15, d0 = (t >> 4) * 4;
  int bc = blockIdx.x;
  const float* rbase = rec + (size_t)bc * CL * RECF;
  float Ad[4];
#pragma unroll
  for (int q = 0; q < 4; q++) Ad[q] = -__expf(A_log[(d0 + q) * DSTA + s]);
  float h[4];
  {
    float4 hv = *reinterpret_cast<const float4*>(hs + (size_t)bc * 512 + t * 4);
    h[0] = hv.x; h[1] = hv.y; h[2] = hv.z; h[3] = hv.w;
  }
#pragma unroll 2
  for (int l = 0; l < CL; l++) {
    const float* rl = rbase + l * RECF;
    float4 dt4 = *reinterpret_cast<const float4*>(rl + d0);
    float4 xc4 = *reinterpret_cast<const float4*>(rl + 32 + d0);
    float bvs = rl[64 + s];
    float cvs = rl[80 + s];
    float dts[4] = {dt4.x, dt4.y, dt4.z, dt4.w};
    float xcs[4] = {xc4.x, xc4.y, xc4.z, xc4.w};
    float y[4];
#pragma unroll
    for (int q = 0; q < 4; q++) {
      float a = __expf(dts[q] * Ad[q]);
      h[q] = fmaf(a, h[q], dts[q] * bvs * xcs[q]);
      y[q] = cvs * h[q];
    }
#pragma unroll
    for (int m = 1; m < 16; m <<= 1) {
#pragma unroll
      for (int q = 0; q < 4; q++) y[q] += __shfl_xor(y[q], m);
    }
    if (s == 0) {
#pragma unroll
      for (int q = 0; q < 4; q++) yv[l][d0 + q] = y[q];
    }
  }
  __syncthreads();
  // epilogue: thread t == row l within chunk
  long r = (long)bc * CL + t;
  const float* rl = rbase + t * RECF;
  float yo[32];
#pragma unroll
  for (int d = 0; d < 32; d++) {
    float xcv = rl[32 + d];
    float zz = rl[96 + d];
    yo[d] = (yv[t][d] + Dskip[d] * xcv) * fsilu(zz);
  }
  float x1[16];
#pragma unroll
  for (int k = 0; k < 16; k++) x1[k] = 0.f;
#pragma unroll
  for (int d = 0; d < 32; d++) {
    float v = yo[d];
#pragma unroll
    for (int k = 0; k < 16; k++) x1[k] = fmaf(v, opw[d * 16 + k], x1[k]);
  }
  float xres[16];
  {
    const float4* xp = reinterpret_cast<const float4*>(x + r * DMOD);
    float4 v0 = xp[0], v1 = xp[1], v2 = xp[2], v3 = xp[3];
    float xo[16] = {v0.x, v0.y, v0.z, v0.w, v1.x, v1.y, v1.z, v1.w,
                    v2.x, v2.y, v2.z, v2.w, v3.x, v3.y, v3.z, v3.w};
#pragma unroll
    for (int i = 0; i < 16; i++) xres[i] = x1[i] + xo[i];
  }
  float ss = 0.f;
#pragma unroll
  for (int i = 0; i < 16; i++) ss += xres[i] * xres[i];
  float inv2 = rsqrtf(ss * (1.f / 16.f) + 1e-6f);
  float x2[16];
#pragma unroll
  for (int i = 0; i < 16; i++) x2[i] = xres[i] * inv2 * rms2w[i];
  float h1[32];
#pragma unroll
  for (int j = 0; j < 32; j++) h1[j] = f1b[j];
#pragma unroll
  for (int i = 0; i < 16; i++) {
    float v = x2[i];
#pragma unroll
    for (int j = 0; j < 32; j++) h1[j] = fmaf(v, f1w[i * 32 + j], h1[j]);
  }
#pragma unroll
  for (int j = 0; j < 32; j++) h1[j] = fmaxf(h1[j], 0.f);
  float h2[32];
#pragma unroll
  for (int j = 0; j < 32; j++) h2[j] = f2b[j];
#pragma unroll
  for (int i = 0; i < 32; i++) {
    float v = h1[i];
#pragma unroll
    for (int j = 0; j < 32; j++) h2[j] = fmaf(v, f2w[i * 32 + j], h2[j]);
  }
#pragma unroll
  for (int j = 0; j < 32; j++) h2[j] = fmaxf(h2[j], 0.f);
  float x3[16];
#pragma unroll
  for (int k = 0; k < 16; k++) x3[k] = f3b[k];
#pragma unroll
  for (int i = 0; i < 32; i++) {
    float v = h2[i];
#pragma unroll
    for (int k = 0; k < 16; k++) x3[k] = fmaf(v, f3w[i * 16 + k], x3[k]);
  }
  float* orow = out + r * DMOD;
#pragma unroll
  for (int k = 0; k < 16; k += 4) {
    *reinterpret_cast<float4*>(orow + k) = make_float4(
        xres[k] + x3[k], xres[k + 1] + x3[k + 1], xres[k + 2] + x3[k + 2],
        xres[k + 3] + x3[k + 3]);
  }
}

extern "C" void kernel_launch(void* const* d_in, const int* in_sizes, int n_in,
                              void* d_out, int out_size, void* d_ws,
                              size_t ws_size, hipStream_t stream) {
  const float* x = (const float*)d_in[0];
  const float* rms1w = (const float*)d_in[1];
  const float* ipw = (const float*)d_in[2];
  const float* cw = (const float*)d_in[3];
  const float* cb = (const float*)d_in[4];
  const float* xpw = (const float*)d_in[5];
  const float* dtw = (const float*)d_in[6];
  const float* dtb = (const float*)d_in[7];
  const float* A_log = (const float*)d_in[8];
  const float* Dskip = (const float*)d_in[9];
  const float* opw = (const float*)d_in[10];
  const float* rms2w = (const float*)d_in[11];
  const float* f1w = (const float*)d_in[12];
  const float* f1b = (const float*)d_in[13];
  const float* f2w = (const float*)d_in[14];
  const float* f2b = (const float*)d_in[15];
  const float* f3w = (const float*)d_in[16];
  const float* f3b = (const float*)d_in[17];
  float* out = (float*)d_out;

  float* rec = (float*)d_ws;                 // NROWS*128 floats (64 MiB)
  float* Pb = rec + (size_t)NROWS * RECF;    // SUMN floats
  float* Hb = Pb + (size_t)SUMN;             // SUMN floats
  float* hsb = Hb + (size_t)SUMN;            // SUMN floats

  hipLaunchKernelGGL(k_prep, dim3(NROWS / 256), dim3(256), 0, stream, x, rms1w,
                     ipw, cw, cb, xpw, dtw, dtb, rec);
  hipLaunchKernelGGL(k_chunk, dim3(NBAT * NCH), dim3(128), 0, stream, rec,
                     A_log, Pb, Hb);
  hipLaunchKernelGGL(k_combine, dim3(NBAT), dim3(512), 0, stream, Pb, Hb, hsb);
  hipLaunchKernelGGL(k_out, dim3(NBAT * NCH), dim3(128), 0, stream, rec, x,
                     A_log, hsb, Dskip, opw, rms2w, f1w, f1b, f2w, f2b, f3w,
                     f3b, out);
}

// Round 2
// 160.268 us; speedup vs baseline: 1.0553x; 1.0553x over previous
//
#include <hip/hip_runtime.h>

#define LSEQ 8192
#define NBAT 16
#define DMOD 16
#define DINN 32
#define DSTA 16
#define CL   64
#define NCH  (LSEQ / CL)            // 128
#define NCHT (NBAT * NCH)           // 2048
#define RECF 96                     // floats per row record (dt|xc|B|C)
#define NROWS (NBAT * LSEQ)         // 131072
#define SUMN ((size_t)NCHT * 512)
#define SMS  100                    // LDS row stride (96+4: bank de-phase)

__device__ __forceinline__ float fsilu(float v) { return v / (1.f + __expf(-v)); }
__device__ __forceinline__ float fsoftplus(float v) {
  return v > 20.f ? v : __logf(1.f + __expf(v));
}

__device__ __forceinline__ void load_x_row(const float* __restrict__ x, long r,
                                           float* __restrict__ xr) {
  const float4* xp = reinterpret_cast<const float4*>(x + r * DMOD);
  float4 v0 = xp[0], v1 = xp[1], v2 = xp[2], v3 = xp[3];
  xr[0] = v0.x; xr[1] = v0.y; xr[2] = v0.z; xr[3] = v0.w;
  xr[4] = v1.x; xr[5] = v1.y; xr[6] = v1.z; xr[7] = v1.w;
  xr[8] = v2.x; xr[9] = v2.y; xr[10] = v2.z; xr[11] = v2.w;
  xr[12] = v3.x; xr[13] = v3.y; xr[14] = v3.z; xr[15] = v3.w;
}

// xm[32] = rmsnorm(x_row) @ in_proj_w[:, 0:32]
__device__ __forceinline__ void inproj_xm(const float* __restrict__ x,
                                          const float* __restrict__ rms1w,
                                          const float* __restrict__ ipw, long r,
                                          float* __restrict__ xm) {
  float xr[16];
  load_x_row(x, r, xr);
  float ss = 0.f;
#pragma unroll
  for (int i = 0; i < 16; i++) ss += xr[i] * xr[i];
  float inv = rsqrtf(ss * (1.f / 16.f) + 1e-6f);
  float x0[16];
#pragma unroll
  for (int i = 0; i < 16; i++) x0[i] = xr[i] * inv * rms1w[i];
  float acc[32];
#pragma unroll
  for (int k = 0; k < 32; k++) acc[k] = 0.f;
#pragma unroll
  for (int i = 0; i < 16; i++) {
    float xi = x0[i];
#pragma unroll
    for (int k = 0; k < 32; k++) acc[k] = fmaf(xi, ipw[i * 64 + k], acc[k]);
  }
#pragma unroll
  for (int k = 0; k < 32; k++) xm[k] = acc[k];
}

// K1: per-row prep. Record (96 floats): [0:32)=dt [32:64)=xc [64:80)=B [80:96)=C
__global__ __launch_bounds__(256) void k_prep(
    const float* __restrict__ x, const float* __restrict__ rms1w,
    const float* __restrict__ ipw, const float* __restrict__ cw,
    const float* __restrict__ cb, const float* __restrict__ xpw,
    const float* __restrict__ dtw, const float* __restrict__ dtb,
    float* __restrict__ rec) {
  __shared__ float xmv[256 + 3][DINN + 1];
  int tid = threadIdx.x;
  long row0 = (long)blockIdx.x * 256;
  long r = row0 + tid;
  if (tid < 3) {
    int l0 = (int)(row0 & (LSEQ - 1));
    int lh = l0 - 3 + tid;
    float xmh[32];
    if (lh < 0) {
#pragma unroll
      for (int d = 0; d < 32; d++) xmh[d] = 0.f;
    } else {
      inproj_xm(x, rms1w, ipw, row0 - 3 + tid, xmh);
    }
#pragma unroll
    for (int d = 0; d < 32; d++) xmv[tid][d] = xmh[d];
  }
  float xm[32];
  inproj_xm(x, rms1w, ipw, r, xm);
#pragma unroll
  for (int d = 0; d < 32; d++) xmv[tid + 3][d] = xm[d];
  __syncthreads();
  // causal depthwise conv + silu
  float xc[32];
#pragma unroll
  for (int d = 0; d < 32; d++) {
    float c = cb[d];
#pragma unroll
    for (int k = 0; k < 4; k++) c = fmaf(cw[d * 4 + k], xmv[tid + k][d], c);
    xc[d] = fsilu(c);
  }
  // x_proj: proj[33] = xc @ xpw[32][33]
  float proj[33];
#pragma unroll
  for (int k = 0; k < 33; k++) proj[k] = 0.f;
#pragma unroll
  for (int d = 0; d < 32; d++) {
    float v = xc[d];
#pragma unroll
    for (int k = 0; k < 33; k++) proj[k] = fmaf(v, xpw[d * 33 + k], proj[k]);
  }
  float* rrec = rec + (size_t)r * RECF;
#pragma unroll
  for (int d = 0; d < 32; d += 4) {
    float dtv0 = fsoftplus(proj[0] * dtw[d + 0] + dtb[d + 0]);
    float dtv1 = fsoftplus(proj[0] * dtw[d + 1] + dtb[d + 1]);
    float dtv2 = fsoftplus(proj[0] * dtw[d + 2] + dtb[d + 2]);
    float dtv3 = fsoftplus(proj[0] * dtw[d + 3] + dtb[d + 3]);
    *reinterpret_cast<float4*>(rrec + d) = make_float4(dtv0, dtv1, dtv2, dtv3);
    *reinterpret_cast<float4*>(rrec + 32 + d) =
        make_float4(xc[d], xc[d + 1], xc[d + 2], xc[d + 3]);
  }
#pragma unroll
  for (int k = 0; k < 16; k += 4) {
    *reinterpret_cast<float4*>(rrec + 64 + k) =
        make_float4(proj[1 + k], proj[2 + k], proj[3 + k], proj[4 + k]);
    *reinterpret_cast<float4*>(rrec + 80 + k) =
        make_float4(proj[17 + k], proj[18 + k], proj[19 + k], proj[20 + k]);
  }
}

// Bulk-stage one chunk's records (CL rows x 96 floats) into LDS (stride SMS).
__device__ __forceinline__ void stage_chunk(const float* __restrict__ rbase,
                                            float* __restrict__ sm, int t) {
#pragma unroll
  for (int i = 0; i < (CL * RECF) / (128 * 4); i++) {  // 12 iters
    int idx = i * 512 + t * 4;
    int row = idx / RECF;
    int off = idx + 4 * row;  // row*SMS + col
    float4 v = *reinterpret_cast<const float4*>(rbase + idx);
    *reinterpret_cast<float4*>(&sm[off]) = v;
  }
}

// K2: per-chunk local scan -> P (decay product), H (state with h0=0)
__global__ __launch_bounds__(128) void k_chunk(const float* __restrict__ rec,
                                               const float* __restrict__ A_log,
                                               float* __restrict__ Pb,
                                               float* __restrict__ Hb) {
  __shared__ float sm[CL * SMS];
  int t = threadIdx.x, bc = blockIdx.x;
  stage_chunk(rec + (size_t)bc * CL * RECF, sm, t);
  __syncthreads();
  int d = t >> 2, s4 = (t & 3) << 2;
  float4 al = *reinterpret_cast<const float4*>(A_log + d * DSTA + s4);
  float Ad[4] = {-__expf(al.x), -__expf(al.y), -__expf(al.z), -__expf(al.w)};
  float H[4] = {0.f, 0.f, 0.f, 0.f};
  float sumdt = 0.f;
#pragma unroll 4
  for (int l = 0; l < CL; l++) {
    const float* rl = &sm[l * SMS];
    float dt = rl[d];
    float xcv = rl[32 + d];
    float4 b4 = *reinterpret_cast<const float4*>(rl + 64 + s4);
    float dx = dt * xcv;
    sumdt += dt;
    float a;
    a = __expf(dt * Ad[0]); H[0] = fmaf(a, H[0], dx * b4.x);
    a = __expf(dt * Ad[1]); H[1] = fmaf(a, H[1], dx * b4.y);
    a = __expf(dt * Ad[2]); H[2] = fmaf(a, H[2], dx * b4.z);
    a = __expf(dt * Ad[3]); H[3] = fmaf(a, H[3], dx * b4.w);
  }
  size_t base = (size_t)bc * 512 + (size_t)(d * 16 + s4);
  *reinterpret_cast<float4*>(Pb + base) =
      make_float4(__expf(sumdt * Ad[0]), __expf(sumdt * Ad[1]),
                  __expf(sumdt * Ad[2]), __expf(sumdt * Ad[3]));
  *reinterpret_cast<float4*>(Hb + base) = make_float4(H[0], H[1], H[2], H[3]);
}

// K3: exclusive scan over chunks; one thread per (batch, state)
__global__ __launch_bounds__(64) void k_combine(const float* __restrict__ Pb,
                                                const float* __restrict__ Hb,
                                                float* __restrict__ hs) {
  int g = blockIdx.x * 64 + threadIdx.x;  // 8192 scans
  int b = g >> 9, st = g & 511;
  size_t base = (size_t)b * NCH * 512 + st;
  float h = 0.f;
#pragma unroll 4
  for (int c = 0; c < NCH; c++) {
    size_t o = base + (size_t)c * 512;
    hs[o] = h;
    h = fmaf(Pb[o], h, Hb[o]);
  }
}

// K4: per-chunk scan with outputs + fused epilogue
__global__ __launch_bounds__(128) void k_out(
    const float* __restrict__ rec, const float* __restrict__ x,
    const float* __restrict__ A_log, const float* __restrict__ hs,
    const float* __restrict__ rms1w, const float* __restrict__ ipw,
    const float* __restrict__ Dskip, const float* __restrict__ opw,
    const float* __restrict__ rms2w, const float* __restrict__ f1w,
    const float* __restrict__ f1b, const float* __restrict__ f2w,
    const float* __restrict__ f2b, const float* __restrict__ f3w,
    const float* __restrict__ f3b, float* __restrict__ out) {
  __shared__ float sm[CL * SMS];
  __shared__ float yv[CL][DINN + 1];
  int t = threadIdx.x, bc = blockIdx.x;
  stage_chunk(rec + (size_t)bc * CL * RECF, sm, t);
  __syncthreads();
  int d = t >> 2, s4 = (t & 3) << 2;
  float4 al = *reinterpret_cast<const float4*>(A_log + d * DSTA + s4);
  float Ad[4] = {-__expf(al.x), -__expf(al.y), -__expf(al.z), -__expf(al.w)};
  float h[4];
  {
    float4 hv = *reinterpret_cast<const float4*>(hs + (size_t)bc * 512 +
                                                 (size_t)(d * 16 + s4));
    h[0] = hv.x; h[1] = hv.y; h[2] = hv.z; h[3] = hv.w;
  }
#pragma unroll 4
  for (int l = 0; l < CL; l++) {
    const float* rl = &sm[l * SMS];
    float dt = rl[d];
    float xcv = rl[32 + d];
    float4 b4 = *reinterpret_cast<const float4*>(rl + 64 + s4);
    float4 c4 = *reinterpret_cast<const float4*>(rl + 80 + s4);
    float dx = dt * xcv;
    float a;
    a = __expf(dt * Ad[0]); h[0] = fmaf(a, h[0], dx * b4.x);
    a = __expf(dt * Ad[1]); h[1] = fmaf(a, h[1], dx * b4.y);
    a = __expf(dt * Ad[2]); h[2] = fmaf(a, h[2], dx * b4.z);
    a = __expf(dt * Ad[3]); h[3] = fmaf(a, h[3], dx * b4.w);
    float y = c4.x * h[0];
    y = fmaf(c4.y, h[1], y);
    y = fmaf(c4.z, h[2], y);
    y = fmaf(c4.w, h[3], y);
    y += __shfl_xor(y, 1);
    y += __shfl_xor(y, 2);
    if ((t & 3) == 0) yv[l][d] = y;
  }
  __syncthreads();
  if (t < CL) {
    long r = (long)bc * CL + t;
    const float* rl = &sm[t * SMS];
    float xcv[32];
#pragma unroll
    for (int d0 = 0; d0 < 32; d0 += 4) {
      float4 v = *reinterpret_cast<const float4*>(rl + 32 + d0);
      xcv[d0] = v.x; xcv[d0 + 1] = v.y; xcv[d0 + 2] = v.z; xcv[d0 + 3] = v.w;
    }
    // recompute z from x row (also used for residual)
    float xr[16];
    load_x_row(x, r, xr);
    float ss = 0.f;
#pragma unroll
    for (int i = 0; i < 16; i++) ss += xr[i] * xr[i];
    float inv1 = rsqrtf(ss * (1.f / 16.f) + 1e-6f);
    float x0[16];
#pragma unroll
    for (int i = 0; i < 16; i++) x0[i] = xr[i] * inv1 * rms1w[i];
    float zv[32];
#pragma unroll
    for (int k = 0; k < 32; k++) zv[k] = 0.f;
#pragma unroll
    for (int i = 0; i < 16; i++) {
      float xi = x0[i];
#pragma unroll
      for (int k = 0; k < 32; k++)
        zv[k] = fmaf(xi, ipw[i * 64 + 32 + k], zv[k]);
    }
    float yo[32];
#pragma unroll
    for (int d0 = 0; d0 < 32; d0++)
      yo[d0] = (yv[t][d0] + Dskip[d0] * xcv[d0]) * fsilu(zv[d0]);
    float x1[16];
#pragma unroll
    for (int k = 0; k < 16; k++) x1[k] = 0.f;
#pragma unroll
    for (int d0 = 0; d0 < 32; d0++) {
      float v = yo[d0];
#pragma unroll
      for (int k = 0; k < 16; k++) x1[k] = fmaf(v, opw[d0 * 16 + k], x1[k]);
    }
    float xres[16];
#pragma unroll
    for (int i = 0; i < 16; i++) xres[i] = x1[i] + xr[i];
    float s2 = 0.f;
#pragma unroll
    for (int i = 0; i < 16; i++) s2 += xres[i] * xres[i];
    float inv2 = rsqrtf(s2 * (1.f / 16.f) + 1e-6f);
    float x2[16];
#pragma unroll
    for (int i = 0; i < 16; i++) x2[i] = xres[i] * inv2 * rms2w[i];
    float h1[32];
#pragma unroll
    for (int j = 0; j < 32; j++) h1[j] = f1b[j];
#pragma unroll
    for (int i = 0; i < 16; i++) {
      float v = x2[i];
#pragma unroll
      for (int j = 0; j < 32; j++) h1[j] = fmaf(v, f1w[i * 32 + j], h1[j]);
    }
#pragma unroll
    for (int j = 0; j < 32; j++) h1[j] = fmaxf(h1[j], 0.f);
    float h2[32];
#pragma unroll
    for (int j = 0; j < 32; j++) h2[j] = f2b[j];
#pragma unroll
    for (int i = 0; i < 32; i++) {
      float v = h1[i];
#pragma unroll
      for (int j = 0; j < 32; j++) h2[j] = fmaf(v, f2w[i * 32 + j], h2[j]);
    }
#pragma unroll
    for (int j = 0; j < 32; j++) h2[j] = fmaxf(h2[j], 0.f);
    float x3[16];
#pragma unroll
    for (int k = 0; k < 16; k++) x3[k] = f3b[k];
#pragma unroll
    for (int i = 0; i < 32; i++) {
      float v = h2[i];
#pragma unroll
      for (int k = 0; k < 16; k++) x3[k] = fmaf(v, f3w[i * 16 + k], x3[k]);
    }
    float* orow = out + r * DMOD;
#pragma unroll
    for (int k = 0; k < 16; k += 4) {
      *reinterpret_cast<float4*>(orow + k) = make_float4(
          xres[k] + x3[k], xres[k + 1] + x3[k + 1], xres[k + 2] + x3[k + 2],
          xres[k + 3] + x3[k + 3]);
    }
  }
}

extern "C" void kernel_launch(void* const* d_in, const int* in_sizes, int n_in,
                              void* d_out, int out_size, void* d_ws,
                              size_t ws_size, hipStream_t stream) {
  const float* x = (const float*)d_in[0];
  const float* rms1w = (const float*)d_in[1];
  const float* ipw = (const float*)d_in[2];
  const float* cw = (const float*)d_in[3];
  const float* cb = (const float*)d_in[4];
  const float* xpw = (const float*)d_in[5];
  const float* dtw = (const float*)d_in[6];
  const float* dtb = (const float*)d_in[7];
  const float* A_log = (const float*)d_in[8];
  const float* Dskip = (const float*)d_in[9];
  const float* opw = (const float*)d_in[10];
  const float* rms2w = (const float*)d_in[11];
  const float* f1w = (const float*)d_in[12];
  const float* f1b = (const float*)d_in[13];
  const float* f2w = (const float*)d_in[14];
  const float* f2b = (const float*)d_in[15];
  const float* f3w = (const float*)d_in[16];
  const float* f3b = (const float*)d_in[17];
  float* out = (float*)d_out;

  float* rec = (float*)d_ws;                     // 48 MiB
  float* Pb = rec + (size_t)NROWS * RECF;        // 4 MiB
  float* Hb = Pb + SUMN;                         // 4 MiB
  float* hsb = Hb + SUMN;                        // 4 MiB

  hipLaunchKernelGGL(k_prep, dim3(NROWS / 256), dim3(256), 0, stream, x, rms1w,
                     ipw, cw, cb, xpw, dtw, dtb, rec);
  hipLaunchKernelGGL(k_chunk, dim3(NCHT), dim3(128), 0, stream, rec, A_log, Pb,
                     Hb);
  hipLaunchKernelGGL(k_combine, dim3((NBAT * 512) / 64), dim3(64), 0, stream,
                     Pb, Hb, hsb);
  hipLaunchKernelGGL(k_out, dim3(NCHT), dim3(128), 0, stream, rec, x, A_log,
                     hsb, rms1w, ipw, Dskip, opw, rms2w, f1w, f1b, f2w, f2b,
                     f3w, f3b, out);
}

// Round 3
// 137.433 us; speedup vs baseline: 1.2306x; 1.1662x over previous
//
#include <hip/hip_runtime.h>

#define LSEQ 8192
#define NBAT 16
#define DMOD 16
#define DINN 32
#define DSTA 16
#define CL   64
#define NCH  (LSEQ / CL)            // 128
#define NCHT (NBAT * NCH)           // 2048
#define RECF 96                     // floats per row record (dt|xc|B|C)
#define NROWS (NBAT * LSEQ)         // 131072
#define SUMN ((size_t)NCHT * 512)
#define SMS  100                    // k_scan LDS row stride
#define SMS2 84                     // k_chunk LDS row stride (80 staged)

typedef __attribute__((ext_vector_type(8))) short bf16x8;
typedef __attribute__((ext_vector_type(4))) float f32x4;

__device__ __forceinline__ float fsilu(float v) { return v / (1.f + __expf(-v)); }
__device__ __forceinline__ float fsoftplus(float v) {
  return v > 20.f ? v : __logf(1.f + __expf(v));
}
__device__ __forceinline__ short f2bf(float f) {
  union { float f; unsigned u; } v; v.f = f;
  unsigned r = (v.u + 0x7fffu + ((v.u >> 16) & 1u)) >> 16;
  return (short)r;
}

__device__ __forceinline__ void load_x_row(const float* __restrict__ x, long r,
                                           float* __restrict__ xr) {
  const float4* xp = reinterpret_cast<const float4*>(x + r * DMOD);
  float4 v0 = xp[0], v1 = xp[1], v2 = xp[2], v3 = xp[3];
  xr[0] = v0.x; xr[1] = v0.y; xr[2] = v0.z; xr[3] = v0.w;
  xr[4] = v1.x; xr[5] = v1.y; xr[6] = v1.z; xr[7] = v1.w;
  xr[8] = v2.x; xr[9] = v2.y; xr[10] = v2.z; xr[11] = v2.w;
  xr[12] = v3.x; xr[13] = v3.y; xr[14] = v3.z; xr[15] = v3.w;
}

// xm[32] = rmsnorm(x_row) @ in_proj_w[:, 0:32]
__device__ __forceinline__ void inproj_xm(const float* __restrict__ x,
                                          const float* __restrict__ rms1w,
                                          const float* __restrict__ ipw, long r,
                                          float* __restrict__ xm) {
  float xr[16];
  load_x_row(x, r, xr);
  float ss = 0.f;
#pragma unroll
  for (int i = 0; i < 16; i++) ss += xr[i] * xr[i];
  float inv = rsqrtf(ss * (1.f / 16.f) + 1e-6f);
  float x0[16];
#pragma unroll
  for (int i = 0; i < 16; i++) x0[i] = xr[i] * inv * rms1w[i];
  float acc[32];
#pragma unroll
  for (int k = 0; k < 32; k++) acc[k] = 0.f;
#pragma unroll
  for (int i = 0; i < 16; i++) {
    float xi = x0[i];
#pragma unroll
    for (int k = 0; k < 32; k++) acc[k] = fmaf(xi, ipw[i * 64 + k], acc[k]);
  }
#pragma unroll
  for (int k = 0; k < 32; k++) xm[k] = acc[k];
}

// K1: per-row prep. Record (96 floats): [0:32)=dt [32:64)=xc [64:80)=B [80:96)=C
__global__ __launch_bounds__(256) void k_prep(
    const float* __restrict__ x, const float* __restrict__ rms1w,
    const float* __restrict__ ipw, const float* __restrict__ cw,
    const float* __restrict__ cb, const float* __restrict__ xpw,
    const float* __restrict__ dtw, const float* __restrict__ dtb,
    float* __restrict__ rec) {
  __shared__ float xmv[256 + 3][DINN + 1];
  int tid = threadIdx.x;
  long row0 = (long)blockIdx.x * 256;
  long r = row0 + tid;
  if (tid < 3) {
    int l0 = (int)(row0 & (LSEQ - 1));
    int lh = l0 - 3 + tid;
    float xmh[32];
    if (lh < 0) {
#pragma unroll
      for (int d = 0; d < 32; d++) xmh[d] = 0.f;
    } else {
      inproj_xm(x, rms1w, ipw, row0 - 3 + tid, xmh);
    }
#pragma unroll
    for (int d = 0; d < 32; d++) xmv[tid][d] = xmh[d];
  }
  float xm[32];
  inproj_xm(x, rms1w, ipw, r, xm);
#pragma unroll
  for (int d = 0; d < 32; d++) xmv[tid + 3][d] = xm[d];
  __syncthreads();
  float xc[32];
#pragma unroll
  for (int d = 0; d < 32; d++) {
    float c = cb[d];
#pragma unroll
    for (int k = 0; k < 4; k++) c = fmaf(cw[d * 4 + k], xmv[tid + k][d], c);
    xc[d] = fsilu(c);
  }
  float proj[33];
#pragma unroll
  for (int k = 0; k < 33; k++) proj[k] = 0.f;
#pragma unroll
  for (int d = 0; d < 32; d++) {
    float v = xc[d];
#pragma unroll
    for (int k = 0; k < 33; k++) proj[k] = fmaf(v, xpw[d * 33 + k], proj[k]);
  }
  float* rrec = rec + (size_t)r * RECF;
#pragma unroll
  for (int d = 0; d < 32; d += 4) {
    float dtv0 = fsoftplus(proj[0] * dtw[d + 0] + dtb[d + 0]);
    float dtv1 = fsoftplus(proj[0] * dtw[d + 1] + dtb[d + 1]);
    float dtv2 = fsoftplus(proj[0] * dtw[d + 2] + dtb[d + 2]);
    float dtv3 = fsoftplus(proj[0] * dtw[d + 3] + dtb[d + 3]);
    *reinterpret_cast<float4*>(rrec + d) = make_float4(dtv0, dtv1, dtv2, dtv3);
    *reinterpret_cast<float4*>(rrec + 32 + d) =
        make_float4(xc[d], xc[d + 1], xc[d + 2], xc[d + 3]);
  }
#pragma unroll
  for (int k = 0; k < 16; k += 4) {
    *reinterpret_cast<float4*>(rrec + 64 + k) =
        make_float4(proj[1 + k], proj[2 + k], proj[3 + k], proj[4 + k]);
    *reinterpret_cast<float4*>(rrec + 80 + k) =
        make_float4(proj[17 + k], proj[18 + k], proj[19 + k], proj[20 + k]);
  }
}

// K2: per-chunk local scan -> P (decay), H (state from h0=0). Stages 80 floats.
__global__ __launch_bounds__(128) void k_chunk(const float* __restrict__ rec,
                                               const float* __restrict__ A_log,
                                               float* __restrict__ Pb,
                                               float* __restrict__ Hb) {
  __shared__ float sm[CL * SMS2];
  int t = threadIdx.x, bc = blockIdx.x;
  {
    const float* rbase = rec + (size_t)bc * CL * RECF;
    int row = t >> 1;
#pragma unroll
    for (int i = 0; i < 10; i++) {
      int col4 = (t & 1) * 10 + i;
      float4 v = *reinterpret_cast<const float4*>(rbase + row * RECF + col4 * 4);
      *reinterpret_cast<float4*>(&sm[row * SMS2 + col4 * 4]) = v;
    }
  }
  __syncthreads();
  int d = t >> 2, s4 = (t & 3) << 2;
  float4 al = *reinterpret_cast<const float4*>(A_log + d * DSTA + s4);
  float Ad[4] = {-__expf(al.x), -__expf(al.y), -__expf(al.z), -__expf(al.w)};
  float H[4] = {0.f, 0.f, 0.f, 0.f};
  float sumdt = 0.f;
#pragma unroll 4
  for (int l = 0; l < CL; l++) {
    const float* rl = &sm[l * SMS2];
    float dt = rl[d];
    float xcv = rl[32 + d];
    float4 b4 = *reinterpret_cast<const float4*>(rl + 64 + s4);
    float dx = dt * xcv;
    sumdt += dt;
    float a;
    a = __expf(dt * Ad[0]); H[0] = fmaf(a, H[0], dx * b4.x);
    a = __expf(dt * Ad[1]); H[1] = fmaf(a, H[1], dx * b4.y);
    a = __expf(dt * Ad[2]); H[2] = fmaf(a, H[2], dx * b4.z);
    a = __expf(dt * Ad[3]); H[3] = fmaf(a, H[3], dx * b4.w);
  }
  size_t base = (size_t)bc * 512 + (size_t)(d * 16 + s4);
  *reinterpret_cast<float4*>(Pb + base) =
      make_float4(__expf(sumdt * Ad[0]), __expf(sumdt * Ad[1]),
                  __expf(sumdt * Ad[2]), __expf(sumdt * Ad[3]));
  *reinterpret_cast<float4*>(Hb + base) = make_float4(H[0], H[1], H[2], H[3]);
}

// K3: exclusive scan over chunks; one thread per (batch, state)
__global__ __launch_bounds__(64) void k_combine(const float* __restrict__ Pb,
                                                const float* __restrict__ Hb,
                                                float* __restrict__ hs) {
  int g = blockIdx.x * 64 + threadIdx.x;
  int b = g >> 9, st = g & 511;
  size_t base = (size_t)b * NCH * 512 + st;
  float h = 0.f;
#pragma unroll 4
  for (int c = 0; c < NCH; c++) {
    size_t o = base + (size_t)c * 512;
    hs[o] = h;
    h = fmaf(Pb[o], h, Hb[o]);
  }
}

// K4: per-chunk scan -> y (pre-gate SSM output) to global
__global__ __launch_bounds__(128) void k_scan(const float* __restrict__ rec,
                                              const float* __restrict__ A_log,
                                              const float* __restrict__ hs,
                                              float* __restrict__ yb) {
  __shared__ float sm[CL * SMS];
  __shared__ float yv[CL * 36];
  int t = threadIdx.x, bc = blockIdx.x;
  {
    const float* rbase = rec + (size_t)bc * CL * RECF;
    int row = t >> 1;
#pragma unroll
    for (int i = 0; i < 12; i++) {
      int col4 = (t & 1) * 12 + i;
      float4 v = *reinterpret_cast<const float4*>(rbase + row * RECF + col4 * 4);
      *reinterpret_cast<float4*>(&sm[row * SMS + col4 * 4]) = v;
    }
  }
  __syncthreads();
  int d = t >> 2, s4 = (t & 3) << 2;
  float4 al = *reinterpret_cast<const float4*>(A_log + d * DSTA + s4);
  float Ad[4] = {-__expf(al.x), -__expf(al.y), -__expf(al.z), -__expf(al.w)};
  float h[4];
  {
    float4 hv = *reinterpret_cast<const float4*>(hs + (size_t)bc * 512 +
                                                 (size_t)(d * 16 + s4));
    h[0] = hv.x; h[1] = hv.y; h[2] = hv.z; h[3] = hv.w;
  }
#pragma unroll 4
  for (int l = 0; l < CL; l++) {
    const float* rl = &sm[l * SMS];
    float dt = rl[d];
    float xcv = rl[32 + d];
    float4 b4 = *reinterpret_cast<const float4*>(rl + 64 + s4);
    float4 c4 = *reinterpret_cast<const float4*>(rl + 80 + s4);
    float dx = dt * xcv;
    float a;
    a = __expf(dt * Ad[0]); h[0] = fmaf(a, h[0], dx * b4.x);
    a = __expf(dt * Ad[1]); h[1] = fmaf(a, h[1], dx * b4.y);
    a = __expf(dt * Ad[2]); h[2] = fmaf(a, h[2], dx * b4.z);
    a = __expf(dt * Ad[3]); h[3] = fmaf(a, h[3], dx * b4.w);
    float y = c4.x * h[0];
    y = fmaf(c4.y, h[1], y);
    y = fmaf(c4.z, h[2], y);
    y = fmaf(c4.w, h[3], y);
    y += __shfl_xor(y, 1);
    y += __shfl_xor(y, 2);
    if ((t & 3) == 0) yv[l * 36 + d] = y;
  }
  __syncthreads();
  if (t < CL) {
    long r = (long)bc * CL + t;
#pragma unroll
    for (int i = 0; i < 8; i++) {
      float4 v = *reinterpret_cast<const float4*>(&yv[t * 36 + i * 4]);
      *reinterpret_cast<float4*>(yb + r * 32 + i * 4) = v;
    }
  }
}

// ---- K5: MFMA epilogue: z-recompute, gate, out_proj, residual, rms2, MLP ----
__device__ __forceinline__ f32x4 mm(bf16x8 a, bf16x8 b, f32x4 c) {
  return __builtin_amdgcn_mfma_f32_16x16x32_bf16(a, b, c, 0, 0, 0);
}
// B-frag: W is [K x N] row-major; col tile ct; kreal rows valid
__device__ __forceinline__ bf16x8 bfrag(const float* __restrict__ W, int ldw,
                                        int coloff, int col, int kg, int kreal) {
  bf16x8 b = {0, 0, 0, 0, 0, 0, 0, 0};
#pragma unroll
  for (int e = 0; e < 8; e++) {
    int k = kg * 8 + e;
    if (k < kreal) b[e] = f2bf(W[k * ldw + coloff + col]);
  }
  return b;
}
// A-frag from LDS row-major (stride 36) f32, rows valid if kg*8 < kreal
__device__ __forceinline__ bf16x8 afrag(const float* sb, int lrow, int kg,
                                        int kreal) {
  bf16x8 a = {0, 0, 0, 0, 0, 0, 0, 0};
  if (kg * 8 < kreal) {
    const float4* p = reinterpret_cast<const float4*>(sb + lrow * 36 + kg * 8);
    float4 u = p[0], v = p[1];
    a[0] = f2bf(u.x); a[1] = f2bf(u.y); a[2] = f2bf(u.z); a[3] = f2bf(u.w);
    a[4] = f2bf(v.x); a[5] = f2bf(v.y); a[6] = f2bf(v.z); a[7] = f2bf(v.w);
  }
  return a;
}

__global__ __launch_bounds__(256) void k_mlp(
    const float* __restrict__ rec, const float* __restrict__ yb,
    const float* __restrict__ x, const float* __restrict__ rms1w,
    const float* __restrict__ ipw, const float* __restrict__ Dskip,
    const float* __restrict__ opw, const float* __restrict__ rms2w,
    const float* __restrict__ f1w, const float* __restrict__ f1b,
    const float* __restrict__ f2w, const float* __restrict__ f2b,
    const float* __restrict__ f3w, const float* __restrict__ f3b,
    float* __restrict__ out) {
  __shared__ float sb[256 * 36];
  int t = threadIdx.x;
  int lane = t & 63, wid = t >> 6;
  int col = lane & 15, kg = lane >> 4;
  long rowbase = (long)blockIdx.x * 256;

  // B-fragments (once per thread)
  bf16x8 Bz0 = bfrag(ipw + 32, 64, 0, col, kg, 16);
  bf16x8 Bz1 = bfrag(ipw + 32, 64, 16, col, kg, 16);
  bf16x8 Bop = bfrag(opw, 16, 0, col, kg, 32);
  bf16x8 Bf1_0 = bfrag(f1w, 32, 0, col, kg, 16);
  bf16x8 Bf1_1 = bfrag(f1w, 32, 16, col, kg, 16);
  bf16x8 Bf2_0 = bfrag(f2w, 32, 0, col, kg, 32);
  bf16x8 Bf2_1 = bfrag(f2w, 32, 16, col, kg, 32);
  bf16x8 Bf3 = bfrag(f3w, 16, 0, col, kg, 32);
  float b1_0 = f1b[col], b1_1 = f1b[16 + col];
  float b2_0 = f2b[col], b2_1 = f2b[16 + col];
  float b3_c = f3b[col];
  float dsk0 = Dskip[col], dsk1 = Dskip[16 + col];
  float rw2 = rms2w[col];

  // Phase A: thread-per-row rmsnorm1 -> x0 into LDS
  {
    float xr[16];
    load_x_row(x, rowbase + t, xr);
    float ss = 0.f;
#pragma unroll
    for (int i = 0; i < 16; i++) ss += xr[i] * xr[i];
    float inv1 = rsqrtf(ss * (1.f / 16.f) + 1e-6f);
#pragma unroll
    for (int i = 0; i < 16; i += 4) {
      float4 w = make_float4(xr[i] * inv1 * rms1w[i],
                             xr[i + 1] * inv1 * rms1w[i + 1],
                             xr[i + 2] * inv1 * rms1w[i + 2],
                             xr[i + 3] * inv1 * rms1w[i + 3]);
      *reinterpret_cast<float4*>(&sb[t * 36 + i]) = w;
    }
  }
  __syncthreads();

  int wr0 = wid * 64;
  const f32x4 zero4 = {0.f, 0.f, 0.f, 0.f};
#pragma unroll 1
  for (int rt = 0; rt < 4; rt++) {
    int tile0 = wr0 + rt * 16;
    // z = x0 @ ipw[:,32:64]
    bf16x8 ax0 = afrag(sb, tile0 + col, kg, 16);
    f32x4 zf0 = mm(ax0, Bz0, zero4);
    f32x4 zf1 = mm(ax0, Bz1, zero4);
    // gating -> yo into sb[tile rows][0:32)
#pragma unroll
    for (int reg = 0; reg < 4; reg++) {
      int lrow = tile0 + kg * 4 + reg;
      long grow = rowbase + lrow;
      float y0 = yb[grow * 32 + col];
      float y1 = yb[grow * 32 + 16 + col];
      float xc0 = rec[grow * RECF + 32 + col];
      float xc1 = rec[grow * RECF + 48 + col];
      float yo0 = (y0 + dsk0 * xc0) * fsilu(zf0[reg]);
      float yo1 = (y1 + dsk1 * xc1) * fsilu(zf1[reg]);
      sb[lrow * 36 + col] = yo0;
      sb[lrow * 36 + 16 + col] = yo1;
    }
    // x1 = yo @ opw
    bf16x8 ayo = afrag(sb, tile0 + col, kg, 32);
    f32x4 x1f = mm(ayo, Bop, zero4);
    // residual + rms2
    float xres[4];
#pragma unroll
    for (int reg = 0; reg < 4; reg++) {
      long grow = rowbase + tile0 + kg * 4 + reg;
      xres[reg] = x1f[reg] + x[grow * 16 + col];
    }
    float x2v[4];
#pragma unroll
    for (int reg = 0; reg < 4; reg++) {
      float ss = xres[reg] * xres[reg];
      ss += __shfl_xor(ss, 1);
      ss += __shfl_xor(ss, 2);
      ss += __shfl_xor(ss, 4);
      ss += __shfl_xor(ss, 8);
      float inv2 = rsqrtf(ss * (1.f / 16.f) + 1e-6f);
      x2v[reg] = xres[reg] * inv2 * rw2;
      sb[(tile0 + kg * 4 + reg) * 36 + col] = x2v[reg];
    }
    // h1 = relu(x2 @ f1w + b1)
    bf16x8 ax2 = afrag(sb, tile0 + col, kg, 16);
    f32x4 h1f0 = mm(ax2, Bf1_0, zero4);
    f32x4 h1f1 = mm(ax2, Bf1_1, zero4);
#pragma unroll
    for (int reg = 0; reg < 4; reg++) {
      int lrow = tile0 + kg * 4 + reg;
      sb[lrow * 36 + col] = fmaxf(h1f0[reg] + b1_0, 0.f);
      sb[lrow * 36 + 16 + col] = fmaxf(h1f1[reg] + b1_1, 0.f);
    }
    // h2 = relu(h1 @ f2w + b2)
    bf16x8 ah1 = afrag(sb, tile0 + col, kg, 32);
    f32x4 h2f0 = mm(ah1, Bf2_0, zero4);
    f32x4 h2f1 = mm(ah1, Bf2_1, zero4);
#pragma unroll
    for (int reg = 0; reg < 4; reg++) {
      int lrow = tile0 + kg * 4 + reg;
      sb[lrow * 36 + col] = fmaxf(h2f0[reg] + b2_0, 0.f);
      sb[lrow * 36 + 16 + col] = fmaxf(h2f1[reg] + b2_1, 0.f);
    }
    // x3 = h2 @ f3w + b3 ; out = xres + x3
    bf16x8 ah2 = afrag(sb, tile0 + col, kg, 32);
    f32x4 x3f = mm(ah2, Bf3, zero4);
#pragma unroll
    for (int reg = 0; reg < 4; reg++) {
      long grow = rowbase + tile0 + kg * 4 + reg;
      out[grow * 16 + col] = xres[reg] + x3f[reg] + b3_c;
    }
  }
}

extern "C" void kernel_launch(void* const* d_in, const int* in_sizes, int n_in,
                              void* d_out, int out_size, void* d_ws,
                              size_t ws_size, hipStream_t stream) {
  const float* x = (const float*)d_in[0];
  const float* rms1w = (const float*)d_in[1];
  const float* ipw = (const float*)d_in[2];
  const float* cw = (const float*)d_in[3];
  const float* cb = (const float*)d_in[4];
  const float* xpw = (const float*)d_in[5];
  const float* dtw = (const float*)d_in[6];
  const float* dtb = (const float*)d_in[7];
  const float* A_log = (const float*)d_in[8];
  const float* Dskip = (const float*)d_in[9];
  const float* opw = (const float*)d_in[10];
  const float* rms2w = (const float*)d_in[11];
  const float* f1w = (const float*)d_in[12];
  const float* f1b = (const float*)d_in[13];
  const float* f2w = (const float*)d_in[14];
  const float* f2b = (const float*)d_in[15];
  const float* f3w = (const float*)d_in[16];
  const float* f3b = (const float*)d_in[17];
  float* out = (float*)d_out;

  float* rec = (float*)d_ws;                 // 48 MiB
  float* Pb = rec + (size_t)NROWS * RECF;    // 4 MiB
  float* Hb = Pb + SUMN;                     // 4 MiB
  float* hsb = Hb + SUMN;                    // 4 MiB
  float* yb = hsb + SUMN;                    // 16.8 MiB

  hipLaunchKernelGGL(k_prep, dim3(NROWS / 256), dim3(256), 0, stream, x, rms1w,
                     ipw, cw, cb, xpw, dtw, dtb, rec);
  hipLaunchKernelGGL(k_chunk, dim3(NCHT), dim3(128), 0, stream, rec, A_log, Pb,
                     Hb);
  hipLaunchKernelGGL(k_combine, dim3((NBAT * 512) / 64), dim3(64), 0, stream,
                     Pb, Hb, hsb);
  hipLaunchKernelGGL(k_scan, dim3(NCHT), dim3(128), 0, stream, rec, A_log, hsb,
                     yb);
  hipLaunchKernelGGL(k_mlp, dim3(NROWS / 256), dim3(256), 0, stream, rec, yb, x,
                     rms1w, ipw, Dskip, opw, rms2w, f1w, f1b, f2w, f2b, f3w,
                     f3b, out);
}

// Round 4
// 130.879 us; speedup vs baseline: 1.2922x; 1.0501x over previous
//
#include <hip/hip_runtime.h>

#define LSEQ 8192
#define NBAT 16
#define DMOD 16
#define DINN 32
#define DSTA 16
#define CL   64
#define NCH  (LSEQ / CL)            // 128
#define NCHT (NBAT * NCH)           // 2048
#define RECC 96                     // comps per row: dt[32]|xc[32]|B[16]|C[16]
#define CHF  (RECC * CL)            // 6144 floats per chunk record
#define NROWS (NBAT * LSEQ)         // 131072
#define SUMN ((size_t)NCHT * 512)
#define SMS  98                     // k_scan LDS row stride (AoS, float2-aligned)
#define SMS2 82                     // k_chunk LDS row stride

typedef __attribute__((ext_vector_type(8))) short bf16x8;
typedef __attribute__((ext_vector_type(4))) float f32x4;

__device__ __forceinline__ float fsilu(float v) { return v / (1.f + __expf(-v)); }
__device__ __forceinline__ float fsoftplus(float v) {
  return v > 20.f ? v : __logf(1.f + __expf(v));
}
__device__ __forceinline__ short f2bf(float f) {
  union { float f; unsigned u; } v; v.f = f;
  unsigned r = (v.u + 0x7fffu + ((v.u >> 16) & 1u)) >> 16;
  return (short)r;
}

__device__ __forceinline__ void load_x_row(const float* __restrict__ x, long r,
                                           float* __restrict__ xr) {
  const float4* xp = reinterpret_cast<const float4*>(x + r * DMOD);
  float4 v0 = xp[0], v1 = xp[1], v2 = xp[2], v3 = xp[3];
  xr[0] = v0.x; xr[1] = v0.y; xr[2] = v0.z; xr[3] = v0.w;
  xr[4] = v1.x; xr[5] = v1.y; xr[6] = v1.z; xr[7] = v1.w;
  xr[8] = v2.x; xr[9] = v2.y; xr[10] = v2.z; xr[11] = v2.w;
  xr[12] = v3.x; xr[13] = v3.y; xr[14] = v3.z; xr[15] = v3.w;
}

// xm[32] = rmsnorm(x_row) @ in_proj_w[:, 0:32]
__device__ __forceinline__ void inproj_xm(const float* __restrict__ x,
                                          const float* __restrict__ rms1w,
                                          const float* __restrict__ ipw, long r,
                                          float* __restrict__ xm) {
  float xr[16];
  load_x_row(x, r, xr);
  float ss = 0.f;
#pragma unroll
  for (int i = 0; i < 16; i++) ss += xr[i] * xr[i];
  float inv = rsqrtf(ss * (1.f / 16.f) + 1e-6f);
  float x0[16];
#pragma unroll
  for (int i = 0; i < 16; i++) x0[i] = xr[i] * inv * rms1w[i];
  float acc[32];
#pragma unroll
  for (int k = 0; k < 32; k++) acc[k] = 0.f;
#pragma unroll
  for (int i = 0; i < 16; i++) {
    float xi = x0[i];
#pragma unroll
    for (int k = 0; k < 32; k++) acc[k] = fmaf(xi, ipw[i * 64 + k], acc[k]);
  }
#pragma unroll
  for (int k = 0; k < 32; k++) xm[k] = acc[k];
}

// K1: one wave per chunk; component-major record -> every store 256B coalesced
__global__ __launch_bounds__(64) void k_prep(
    const float* __restrict__ x, const float* __restrict__ rms1w,
    const float* __restrict__ ipw, const float* __restrict__ cw,
    const float* __restrict__ cb, const float* __restrict__ xpw,
    const float* __restrict__ dtw, const float* __restrict__ dtb,
    float* __restrict__ rec) {
  __shared__ float xmv[CL + 3][DINN + 1];
  int t = threadIdx.x;
  int bc = blockIdx.x;
  long row0 = (long)bc * CL;
  long r = row0 + t;
  int l0 = (int)(row0 & (LSEQ - 1));
  if (t < 3) {
    float xmh[32];
    if (l0 == 0) {
#pragma unroll
      for (int d = 0; d < 32; d++) xmh[d] = 0.f;
    } else {
      inproj_xm(x, rms1w, ipw, row0 - 3 + t, xmh);
    }
#pragma unroll
    for (int d = 0; d < 32; d++) xmv[t][d] = xmh[d];
  }
  float xm[32];
  inproj_xm(x, rms1w, ipw, r, xm);
#pragma unroll
  for (int d = 0; d < 32; d++) xmv[t + 3][d] = xm[d];
  __syncthreads();
  float xc[32];
#pragma unroll
  for (int d = 0; d < 32; d++) {
    float c = cb[d];
#pragma unroll
    for (int k = 0; k < 4; k++) c = fmaf(cw[d * 4 + k], xmv[t + k][d], c);
    xc[d] = fsilu(c);
  }
  float proj[33];
#pragma unroll
  for (int k = 0; k < 33; k++) proj[k] = 0.f;
#pragma unroll
  for (int d = 0; d < 32; d++) {
    float v = xc[d];
#pragma unroll
    for (int k = 0; k < 33; k++) proj[k] = fmaf(v, xpw[d * 33 + k], proj[k]);
  }
  float* cb_ = rec + (size_t)bc * CHF;
#pragma unroll
  for (int d = 0; d < 32; d++) {
    float dtv = fsoftplus(proj[0] * dtw[d] + dtb[d]);
    cb_[d * 64 + t] = dtv;
    cb_[(32 + d) * 64 + t] = xc[d];
  }
#pragma unroll
  for (int k = 0; k < 16; k++) {
    cb_[(64 + k) * 64 + t] = proj[1 + k];
    cb_[(80 + k) * 64 + t] = proj[17 + k];
  }
}

// K2: per-chunk local scan -> P, H.  Stages comps 0..79 transposed into LDS.
__global__ __launch_bounds__(128) void k_chunk(const float* __restrict__ rec,
                                               const float* __restrict__ A_log,
                                               float* __restrict__ Pb,
                                               float* __restrict__ Hb) {
  __shared__ float sm[CL * SMS2];
  int t = threadIdx.x, bc = blockIdx.x;
  const float* cbase = rec + (size_t)bc * CHF;
#pragma unroll
  for (int i = 0; i < 10; i++) {
    int g4 = i * 512 + t * 4;
    int c = g4 >> 6, l = g4 & 63;
    float4 v = *reinterpret_cast<const float4*>(cbase + g4);
    sm[(l + 0) * SMS2 + c] = v.x;
    sm[(l + 1) * SMS2 + c] = v.y;
    sm[(l + 2) * SMS2 + c] = v.z;
    sm[(l + 3) * SMS2 + c] = v.w;
  }
  __syncthreads();
  int d = t >> 2, s4 = (t & 3) << 2;
  float4 al = *reinterpret_cast<const float4*>(A_log + d * DSTA + s4);
  float Ad[4] = {-__expf(al.x), -__expf(al.y), -__expf(al.z), -__expf(al.w)};
  float H[4] = {0.f, 0.f, 0.f, 0.f};
  float sumdt = 0.f;
#pragma unroll 4
  for (int l = 0; l < CL; l++) {
    const float* rl = &sm[l * SMS2];
    float dt = rl[d];
    float xcv = rl[32 + d];
    float2 b01 = *reinterpret_cast<const float2*>(rl + 64 + s4);
    float2 b23 = *reinterpret_cast<const float2*>(rl + 64 + s4 + 2);
    float dx = dt * xcv;
    sumdt += dt;
    float a;
    a = __expf(dt * Ad[0]); H[0] = fmaf(a, H[0], dx * b01.x);
    a = __expf(dt * Ad[1]); H[1] = fmaf(a, H[1], dx * b01.y);
    a = __expf(dt * Ad[2]); H[2] = fmaf(a, H[2], dx * b23.x);
    a = __expf(dt * Ad[3]); H[3] = fmaf(a, H[3], dx * b23.y);
  }
  size_t base = (size_t)bc * 512 + (size_t)(d * 16 + s4);
  *reinterpret_cast<float4*>(Pb + base) =
      make_float4(__expf(sumdt * Ad[0]), __expf(sumdt * Ad[1]),
                  __expf(sumdt * Ad[2]), __expf(sumdt * Ad[3]));
  *reinterpret_cast<float4*>(Hb + base) = make_float4(H[0], H[1], H[2], H[3]);
}

// K3: exclusive scan over chunks; one thread per (batch, state)
__global__ __launch_bounds__(64) void k_combine(const float* __restrict__ Pb,
                                                const float* __restrict__ Hb,
                                                float* __restrict__ hs) {
  int g = blockIdx.x * 64 + threadIdx.x;
  int b = g >> 9, st = g & 511;
  size_t base = (size_t)b * NCH * 512 + st;
  float h = 0.f;
#pragma unroll 4
  for (int c = 0; c < NCH; c++) {
    size_t o = base + (size_t)c * 512;
    hs[o] = h;
    h = fmaf(Pb[o], h, Hb[o]);
  }
}

// K4: per-chunk scan -> y (pre-gate SSM output), component-major [chunk][32][64]
__global__ __launch_bounds__(128) void k_scan(const float* __restrict__ rec,
                                              const float* __restrict__ A_log,
                                              const float* __restrict__ hs,
                                              float* __restrict__ yb) {
  __shared__ float sm[CL * SMS];
  __shared__ float yv[CL * 33];
  int t = threadIdx.x, bc = blockIdx.x;
  const float* cbase = rec + (size_t)bc * CHF;
#pragma unroll
  for (int i = 0; i < 12; i++) {
    int g4 = i * 512 + t * 4;
    int c = g4 >> 6, l = g4 & 63;
    float4 v = *reinterpret_cast<const float4*>(cbase + g4);
    sm[(l + 0) * SMS + c] = v.x;
    sm[(l + 1) * SMS + c] = v.y;
    sm[(l + 2) * SMS + c] = v.z;
    sm[(l + 3) * SMS + c] = v.w;
  }
  __syncthreads();
  int d = t >> 2, s4 = (t & 3) << 2;
  float4 al = *reinterpret_cast<const float4*>(A_log + d * DSTA + s4);
  float Ad[4] = {-__expf(al.x), -__expf(al.y), -__expf(al.z), -__expf(al.w)};
  float h[4];
  {
    float4 hv = *reinterpret_cast<const float4*>(hs + (size_t)bc * 512 +
                                                 (size_t)(d * 16 + s4));
    h[0] = hv.x; h[1] = hv.y; h[2] = hv.z; h[3] = hv.w;
  }
#pragma unroll 4
  for (int l = 0; l < CL; l++) {
    const float* rl = &sm[l * SMS];
    float dt = rl[d];
    float xcv = rl[32 + d];
    float2 b01 = *reinterpret_cast<const float2*>(rl + 64 + s4);
    float2 b23 = *reinterpret_cast<const float2*>(rl + 64 + s4 + 2);
    float2 c01 = *reinterpret_cast<const float2*>(rl + 80 + s4);
    float2 c23 = *reinterpret_cast<const float2*>(rl + 80 + s4 + 2);
    float dx = dt * xcv;
    float a;
    a = __expf(dt * Ad[0]); h[0] = fmaf(a, h[0], dx * b01.x);
    a = __expf(dt * Ad[1]); h[1] = fmaf(a, h[1], dx * b01.y);
    a = __expf(dt * Ad[2]); h[2] = fmaf(a, h[2], dx * b23.x);
    a = __expf(dt * Ad[3]); h[3] = fmaf(a, h[3], dx * b23.y);
    float y = c01.x * h[0];
    y = fmaf(c01.y, h[1], y);
    y = fmaf(c23.x, h[2], y);
    y = fmaf(c23.y, h[3], y);
    y += __shfl_xor(y, 1);
    y += __shfl_xor(y, 2);
    if ((t & 3) == 0) yv[l * 33 + d] = y;
  }
  __syncthreads();
  float* ybase = yb + (size_t)bc * 2048;
#pragma unroll
  for (int i = 0; i < 16; i++) {
    int g = i * 128 + t;
    int d2 = g >> 6, l2 = g & 63;
    ybase[g] = yv[l2 * 33 + d2];
  }
}

// ---- K5: MFMA epilogue ----
__device__ __forceinline__ f32x4 mm(bf16x8 a, bf16x8 b, f32x4 c) {
  return __builtin_amdgcn_mfma_f32_16x16x32_bf16(a, b, c, 0, 0, 0);
}
__device__ __forceinline__ bf16x8 bfrag(const float* __restrict__ W, int ldw,
                                        int coloff, int col, int kg, int kreal) {
  bf16x8 b = {0, 0, 0, 0, 0, 0, 0, 0};
#pragma unroll
  for (int e = 0; e < 8; e++) {
    int k = kg * 8 + e;
    if (k < kreal) b[e] = f2bf(W[k * ldw + coloff + col]);
  }
  return b;
}
__device__ __forceinline__ bf16x8 afrag(const float* sb, int lrow, int kg,
                                        int kreal) {
  bf16x8 a = {0, 0, 0, 0, 0, 0, 0, 0};
  if (kg * 8 < kreal) {
    const float4* p = reinterpret_cast<const float4*>(sb + lrow * 36 + kg * 8);
    float4 u = p[0], v = p[1];
    a[0] = f2bf(u.x); a[1] = f2bf(u.y); a[2] = f2bf(u.z); a[3] = f2bf(u.w);
    a[4] = f2bf(v.x); a[5] = f2bf(v.y); a[6] = f2bf(v.z); a[7] = f2bf(v.w);
  }
  return a;
}

__global__ __launch_bounds__(256) void k_mlp(
    const float* __restrict__ rec, const float* __restrict__ yb,
    const float* __restrict__ x, const float* __restrict__ rms1w,
    const float* __restrict__ ipw, const float* __restrict__ Dskip,
    const float* __restrict__ opw, const float* __restrict__ rms2w,
    const float* __restrict__ f1w, const float* __restrict__ f1b,
    const float* __restrict__ f2w, const float* __restrict__ f2b,
    const float* __restrict__ f3w, const float* __restrict__ f3b,
    float* __restrict__ out) {
  __shared__ float sb[256 * 36];
  int t = threadIdx.x;
  int lane = t & 63, wid = t >> 6;
  int col = lane & 15, kg = lane >> 4;
  long rowbase = (long)blockIdx.x * 256;

  bf16x8 Bz0 = bfrag(ipw + 32, 64, 0, col, kg, 16);
  bf16x8 Bz1 = bfrag(ipw + 32, 64, 16, col, kg, 16);
  bf16x8 Bop = bfrag(opw, 16, 0, col, kg, 32);
  bf16x8 Bf1_0 = bfrag(f1w, 32, 0, col, kg, 16);
  bf16x8 Bf1_1 = bfrag(f1w, 32, 16, col, kg, 16);
  bf16x8 Bf2_0 = bfrag(f2w, 32, 0, col, kg, 32);
  bf16x8 Bf2_1 = bfrag(f2w, 32, 16, col, kg, 32);
  bf16x8 Bf3 = bfrag(f3w, 16, 0, col, kg, 32);
  float b1_0 = f1b[col], b1_1 = f1b[16 + col];
  float b2_0 = f2b[col], b2_1 = f2b[16 + col];
  float b3_c = f3b[col];
  float dsk0 = Dskip[col], dsk1 = Dskip[16 + col];
  float rw2 = rms2w[col];

  {
    float xr[16];
    load_x_row(x, rowbase + t, xr);
    float ss = 0.f;
#pragma unroll
    for (int i = 0; i < 16; i++) ss += xr[i] * xr[i];
    float inv1 = rsqrtf(ss * (1.f / 16.f) + 1e-6f);
#pragma unroll
    for (int i = 0; i < 16; i += 4) {
      float4 w = make_float4(xr[i] * inv1 * rms1w[i],
                             xr[i + 1] * inv1 * rms1w[i + 1],
                             xr[i + 2] * inv1 * rms1w[i + 2],
                             xr[i + 3] * inv1 * rms1w[i + 3]);
      *reinterpret_cast<float4*>(&sb[t * 36 + i]) = w;
    }
  }
  __syncthreads();

  int wr0 = wid * 64;
  int chunk = (int)(rowbase >> 6) + wid;
  const float* xcc = rec + (size_t)chunk * CHF + 32 * 64;
  const float* ybc = yb + (size_t)chunk * 2048;
  const f32x4 zero4 = {0.f, 0.f, 0.f, 0.f};
#pragma unroll 1
  for (int rt = 0; rt < 4; rt++) {
    int tile0 = wr0 + rt * 16;
    bf16x8 ax0 = afrag(sb, tile0 + col, kg, 16);
    f32x4 zf0 = mm(ax0, Bz0, zero4);
    f32x4 zf1 = mm(ax0, Bz1, zero4);
#pragma unroll
    for (int reg = 0; reg < 4; reg++) {
      int lrow = tile0 + kg * 4 + reg;
      int lloc = rt * 16 + kg * 4 + reg;
      float y0 = ybc[col * 64 + lloc];
      float y1 = ybc[(16 + col) * 64 + lloc];
      float xc0 = xcc[col * 64 + lloc];
      float xc1 = xcc[(16 + col) * 64 + lloc];
      float yo0 = (y0 + dsk0 * xc0) * fsilu(zf0[reg]);
      float yo1 = (y1 + dsk1 * xc1) * fsilu(zf1[reg]);
      sb[lrow * 36 + col] = yo0;
      sb[lrow * 36 + 16 + col] = yo1;
    }
    bf16x8 ayo = afrag(sb, tile0 + col, kg, 32);
    f32x4 x1f = mm(ayo, Bop, zero4);
    float xres[4];
#pragma unroll
    for (int reg = 0; reg < 4; reg++) {
      long grow = rowbase + tile0 + kg * 4 + reg;
      xres[reg] = x1f[reg] + x[grow * 16 + col];
    }
    float x2v[4];
#pragma unroll
    for (int reg = 0; reg < 4; reg++) {
      float ss = xres[reg] * xres[reg];
      ss += __shfl_xor(ss, 1);
      ss += __shfl_xor(ss, 2);
      ss += __shfl_xor(ss, 4);
      ss += __shfl_xor(ss, 8);
      float inv2 = rsqrtf(ss * (1.f / 16.f) + 1e-6f);
      x2v[reg] = xres[reg] * inv2 * rw2;
      sb[(tile0 + kg * 4 + reg) * 36 + col] = x2v[reg];
    }
    bf16x8 ax2 = afrag(sb, tile0 + col, kg, 16);
    f32x4 h1f0 = mm(ax2, Bf1_0, zero4);
    f32x4 h1f1 = mm(ax2, Bf1_1, zero4);
#pragma unroll
    for (int reg = 0; reg < 4; reg++) {
      int lrow = tile0 + kg * 4 + reg;
      sb[lrow * 36 + col] = fmaxf(h1f0[reg] + b1_0, 0.f);
      sb[lrow * 36 + 16 + col] = fmaxf(h1f1[reg] + b1_1, 0.f);
    }
    bf16x8 ah1 = afrag(sb, tile0 + col, kg, 32);
    f32x4 h2f0 = mm(ah1, Bf2_0, zero4);
    f32x4 h2f1 = mm(ah1, Bf2_1, zero4);
#pragma unroll
    for (int reg = 0; reg < 4; reg++) {
      int lrow = tile0 + kg * 4 + reg;
      sb[lrow * 36 + col] = fmaxf(h2f0[reg] + b2_0, 0.f);
      sb[lrow * 36 + 16 + col] = fmaxf(h2f1[reg] + b2_1, 0.f);
    }
    bf16x8 ah2 = afrag(sb, tile0 + col, kg, 32);
    f32x4 x3f = mm(ah2, Bf3, zero4);
#pragma unroll
    for (int reg = 0; reg < 4; reg++) {
      long grow = rowbase + tile0 + kg * 4 + reg;
      out[grow * 16 + col] = xres[reg] + x3f[reg] + b3_c;
    }
  }
}

extern "C" void kernel_launch(void* const* d_in, const int* in_sizes, int n_in,
                              void* d_out, int out_size, void* d_ws,
                              size_t ws_size, hipStream_t stream) {
  const float* x = (const float*)d_in[0];
  const float* rms1w = (const float*)d_in[1];
  const float* ipw = (const float*)d_in[2];
  const float* cw = (const float*)d_in[3];
  const float* cb = (const float*)d_in[4];
  const float* xpw = (const float*)d_in[5];
  const float* dtw = (const float*)d_in[6];
  const float* dtb = (const float*)d_in[7];
  const float* A_log = (const float*)d_in[8];
  const float* Dskip = (const float*)d_in[9];
  const float* opw = (const float*)d_in[10];
  const float* rms2w = (const float*)d_in[11];
  const float* f1w = (const float*)d_in[12];
  const float* f1b = (const float*)d_in[13];
  const float* f2w = (const float*)d_in[14];
  const float* f2b = (const float*)d_in[15];
  const float* f3w = (const float*)d_in[16];
  const float* f3b = (const float*)d_in[17];
  float* out = (float*)d_out;

  float* rec = (float*)d_ws;                  // 50.3 MiB
  float* Pb = rec + (size_t)NCHT * CHF;       // 4 MiB
  float* Hb = Pb + SUMN;                      // 4 MiB
  float* hsb = Hb + SUMN;                     // 4 MiB
  float* yb = hsb + SUMN;                     // 16.8 MiB

  hipLaunchKernelGGL(k_prep, dim3(NCHT), dim3(64), 0, stream, x, rms1w, ipw, cw,
                     cb, xpw, dtw, dtb, rec);
  hipLaunchKernelGGL(k_chunk, dim3(NCHT), dim3(128), 0, stream, rec, A_log, Pb,
                     Hb);
  hipLaunchKernelGGL(k_combine, dim3((NBAT * 512) / 64), dim3(64), 0, stream,
                     Pb, Hb, hsb);
  hipLaunchKernelGGL(k_scan, dim3(NCHT), dim3(128), 0, stream, rec, A_log, hsb,
                     yb);
  hipLaunchKernelGGL(k_mlp, dim3(NROWS / 256), dim3(256), 0, stream, rec, yb, x,
                     rms1w, ipw, Dskip, opw, rms2w, f1w, f1b, f2w, f2b, f3w,
                     f3b, out);
}

// Round 5
// 118.826 us; speedup vs baseline: 1.4233x; 1.1014x over previous
//
#include <hip/hip_runtime.h>

#define LSEQ 8192
#define NBAT 16
#define DMOD 16
#define DINN 32
#define DSTA 16
#define CL   64
#define NCH  (LSEQ / CL)            // 128
#define NCHT (NBAT * NCH)           // 2048
#define CHF  (96 * CL)              // 6144 floats per chunk record (comp-major)
#define NROWS (NBAT * LSEQ)         // 131072
#define SUMN ((size_t)NCHT * 512)

typedef __attribute__((ext_vector_type(8))) short bf16x8;
typedef __attribute__((ext_vector_type(4))) float f32x4;

__device__ __forceinline__ float fsilu(float v) { return v / (1.f + __expf(-v)); }
__device__ __forceinline__ float fsoftplus(float v) {
  return v > 20.f ? v : __logf(1.f + __expf(v));
}
__device__ __forceinline__ short f2bf(float f) {
  union { float f; unsigned u; } v; v.f = f;
  unsigned r = (v.u + 0x7fffu + ((v.u >> 16) & 1u)) >> 16;
  return (short)r;
}

__device__ __forceinline__ void load_x_row(const float* __restrict__ x, long r,
                                           float* __restrict__ xr) {
  const float4* xp = reinterpret_cast<const float4*>(x + r * DMOD);
  float4 v0 = xp[0], v1 = xp[1], v2 = xp[2], v3 = xp[3];
  xr[0] = v0.x; xr[1] = v0.y; xr[2] = v0.z; xr[3] = v0.w;
  xr[4] = v1.x; xr[5] = v1.y; xr[6] = v1.z; xr[7] = v1.w;
  xr[8] = v2.x; xr[9] = v2.y; xr[10] = v2.z; xr[11] = v2.w;
  xr[12] = v3.x; xr[13] = v3.y; xr[14] = v3.z; xr[15] = v3.w;
}

// scalar xm (halo rows only): xm[32] = rmsnorm(x_row) @ ipw[:, 0:32]
__device__ __forceinline__ void inproj_xm(const float* __restrict__ x,
                                          const float* __restrict__ rms1w,
                                          const float* __restrict__ ipw, long r,
                                          float* __restrict__ xm) {
  float xr[16];
  load_x_row(x, r, xr);
  float ss = 0.f;
#pragma unroll
  for (int i = 0; i < 16; i++) ss += xr[i] * xr[i];
  float inv = rsqrtf(ss * (1.f / 16.f) + 1e-6f);
  float x0[16];
#pragma unroll
  for (int i = 0; i < 16; i++) x0[i] = xr[i] * inv * rms1w[i];
#pragma unroll
  for (int k = 0; k < 32; k++) xm[k] = 0.f;
#pragma unroll
  for (int i = 0; i < 16; i++) {
    float xi = x0[i];
#pragma unroll
    for (int k = 0; k < 32; k++) xm[k] = fmaf(xi, ipw[i * 64 + k], xm[k]);
  }
}

__device__ __forceinline__ f32x4 mm(bf16x8 a, bf16x8 b, f32x4 c) {
  return __builtin_amdgcn_mfma_f32_16x16x32_bf16(a, b, c, 0, 0, 0);
}
__device__ __forceinline__ bf16x8 bfrag(const float* __restrict__ W, int ldw,
                                        int coloff, int col, int kg, int kreal) {
  bf16x8 b = {0, 0, 0, 0, 0, 0, 0, 0};
#pragma unroll
  for (int e = 0; e < 8; e++) {
    int k = kg * 8 + e;
    if (k < kreal) b[e] = f2bf(W[k * ldw + coloff + col]);
  }
  return b;
}

// ---- K1: MFMA prep.  256 rows (4 chunks) per block.  Comp-major record:
// rec[chunk][c][64], c: dt[0:32) xc[32:64) B[64:80) C[80:96)
__global__ __launch_bounds__(256) void k_prep(
    const float* __restrict__ x, const float* __restrict__ rms1w,
    const float* __restrict__ ipw, const float* __restrict__ cw,
    const float* __restrict__ cb, const float* __restrict__ xpw,
    const float* __restrict__ dtw, const float* __restrict__ dtb,
    float* __restrict__ rec) {
  __shared__ short x0b[259][24];   // x0 bf16 (+3 halo rows) stride 48B
  __shared__ float xmv[259][33];   // xm f32 (+halo); reused as proj[256][33]
  __shared__ short xcb[256][40];   // xc bf16, stride 80B
  int t = threadIdx.x;
  int lane = t & 63, wid = t >> 6;
  int col = lane & 15, kg = lane >> 4;
  long row0 = (long)blockIdx.x * 256;
  int l0 = (int)(row0 & (LSEQ - 1));
  const f32x4 zero4 = {0.f, 0.f, 0.f, 0.f};

  // weight fragments (once)
  bf16x8 Bip0 = bfrag(ipw, 64, 0, col, kg, 16);
  bf16x8 Bip1 = bfrag(ipw, 64, 16, col, kg, 16);
  bf16x8 Bdt, Bb, Bc;
#pragma unroll
  for (int e = 0; e < 8; e++) {
    int k = kg * 8 + e;
    Bdt[e] = (col == 0) ? f2bf(xpw[k * 33]) : (short)0;
    Bb[e] = f2bf(xpw[k * 33 + 1 + col]);
    Bc[e] = f2bf(xpw[k * 33 + 17 + col]);
  }

  // Phase A: rmsnorm -> x0 (bf16 to LDS); 3 halo xm rows scalar
  {
    float xr[16];
    load_x_row(x, row0 + t, xr);
    float ss = 0.f;
#pragma unroll
    for (int i = 0; i < 16; i++) ss += xr[i] * xr[i];
    float inv1 = rsqrtf(ss * (1.f / 16.f) + 1e-6f);
#pragma unroll
    for (int i = 0; i < 4; i++) {
      float a0 = xr[i * 4 + 0] * inv1 * rms1w[i * 4 + 0];
      float a1 = xr[i * 4 + 1] * inv1 * rms1w[i * 4 + 1];
      float a2 = xr[i * 4 + 2] * inv1 * rms1w[i * 4 + 2];
      float a3 = xr[i * 4 + 3] * inv1 * rms1w[i * 4 + 3];
      unsigned u0 = ((unsigned)(unsigned short)f2bf(a0)) |
                    (((unsigned)(unsigned short)f2bf(a1)) << 16);
      unsigned u1 = ((unsigned)(unsigned short)f2bf(a2)) |
                    (((unsigned)(unsigned short)f2bf(a3)) << 16);
      *reinterpret_cast<uint2*>(&x0b[3 + t][i * 4]) = make_uint2(u0, u1);
    }
  }
  if (t < 3) {
    float xmh[32];
    if (l0 == 0) {
#pragma unroll
      for (int d = 0; d < 32; d++) xmh[d] = 0.f;
    } else {
      inproj_xm(x, rms1w, ipw, row0 - 3 + t, xmh);
    }
#pragma unroll
    for (int d = 0; d < 32; d++) xmv[t][d] = xmh[d];
  }
  __syncthreads();

  // Phase B: xm = x0 @ ipw[:, 0:32] via MFMA
  {
    int tile0 = wid * 64;
#pragma unroll
    for (int rt = 0; rt < 4; rt++) {
      int arow = 3 + tile0 + rt * 16 + col;
      bf16x8 a = {0, 0, 0, 0, 0, 0, 0, 0};
      if (kg < 2) a = *reinterpret_cast<const bf16x8*>(&x0b[arow][kg * 8]);
      f32x4 m0 = mm(a, Bip0, zero4);
      f32x4 m1 = mm(a, Bip1, zero4);
      int orow = 3 + tile0 + rt * 16 + kg * 4;
#pragma unroll
      for (int reg = 0; reg < 4; reg++) {
        xmv[orow + reg][col] = m0[reg];
        xmv[orow + reg][col + 16] = m1[reg];
      }
    }
  }
  __syncthreads();

  // Phase C: causal conv + silu (f32, thread-per-row)
  float xc[32];
#pragma unroll
  for (int d = 0; d < 32; d++) {
    float c = cb[d];
#pragma unroll
    for (int k = 0; k < 4; k++) c = fmaf(cw[d * 4 + k], xmv[t + k][d], c);
    xc[d] = fsilu(c);
  }
#pragma unroll
  for (int i = 0; i < 8; i++) {
    unsigned u0 = ((unsigned)(unsigned short)f2bf(xc[i * 4 + 0])) |
                  (((unsigned)(unsigned short)f2bf(xc[i * 4 + 1])) << 16);
    unsigned u1 = ((unsigned)(unsigned short)f2bf(xc[i * 4 + 2])) |
                  (((unsigned)(unsigned short)f2bf(xc[i * 4 + 3])) << 16);
    *reinterpret_cast<uint2*>(&xcb[t][i * 4]) = make_uint2(u0, u1);
  }
  __syncthreads();

  // Phase D: proj = xc @ xpw via MFMA (dt col 0, B cols 1..16, C cols 17..32)
  float* prj = &xmv[0][0];  // reuse (stride 33), rows 0..255
  {
    int tile0 = wid * 64;
#pragma unroll
    for (int rt = 0; rt < 4; rt++) {
      int arow = tile0 + rt * 16 + col;
      bf16x8 a2 = *reinterpret_cast<const bf16x8*>(&xcb[arow][kg * 8]);
      f32x4 pd = mm(a2, Bdt, zero4);
      f32x4 pb = mm(a2, Bb, zero4);
      f32x4 pc = mm(a2, Bc, zero4);
      int orow = tile0 + rt * 16 + kg * 4;
#pragma unroll
      for (int reg = 0; reg < 4; reg++) {
        if (col == 0) prj[(orow + reg) * 33] = pd[reg];
        prj[(orow + reg) * 33 + 1 + col] = pb[reg];
        prj[(orow + reg) * 33 + 17 + col] = pc[reg];
      }
    }
  }
  __syncthreads();

  // Phase E: coalesced comp-major global writes
  {
    int ch = t >> 6, l = t & 63;
    float* base = rec + (size_t)(blockIdx.x * 4 + ch) * CHF;
    float p0 = prj[t * 33];
#pragma unroll
    for (int d = 0; d < 32; d++) {
      base[d * 64 + l] = fsoftplus(p0 * dtw[d] + dtb[d]);
      base[(32 + d) * 64 + l] = xc[d];
    }
#pragma unroll
    for (int i = 0; i < 16; i++) {
      base[(64 + i) * 64 + l] = prj[t * 33 + 1 + i];
      base[(80 + i) * 64 + l] = prj[t * 33 + 17 + i];
    }
  }
}

// ---- K2: per-chunk local scan -> P, H.  Comp-major LDS stride 65.
__global__ __launch_bounds__(128) void k_chunk(const float* __restrict__ rec,
                                               const float* __restrict__ A_log,
                                               float* __restrict__ Pb,
                                               float* __restrict__ Hb) {
  __shared__ float sm[80 * 65];
  int t = threadIdx.x, bc = blockIdx.x;
  const float* cbase = rec + (size_t)bc * CHF;
#pragma unroll
  for (int i = 0; i < 10; i++) {
    int g4 = i * 512 + t * 4;
    int c = g4 >> 6, l = g4 & 63;
    *reinterpret_cast<float4*>(&sm[c * 65 + l]) =
        *reinterpret_cast<const float4*>(cbase + g4);
  }
  __syncthreads();
  int d = t >> 2, s4 = (t & 3) << 2;
  float4 al = *reinterpret_cast<const float4*>(A_log + d * DSTA + s4);
  float Ad[4] = {-__expf(al.x), -__expf(al.y), -__expf(al.z), -__expf(al.w)};
  float H[4] = {0.f, 0.f, 0.f, 0.f};
  float sumdt = 0.f;
  int dof = d * 65, xof = (32 + d) * 65;
  int bof0 = (64 + s4) * 65, bof1 = (65 + s4) * 65, bof2 = (66 + s4) * 65,
      bof3 = (67 + s4) * 65;
#pragma unroll 4
  for (int l = 0; l < CL; l++) {
    float dt = sm[dof + l];
    float xcv = sm[xof + l];
    float dx = dt * xcv;
    sumdt += dt;
    float a;
    a = __expf(dt * Ad[0]); H[0] = fmaf(a, H[0], dx * sm[bof0 + l]);
    a = __expf(dt * Ad[1]); H[1] = fmaf(a, H[1], dx * sm[bof1 + l]);
    a = __expf(dt * Ad[2]); H[2] = fmaf(a, H[2], dx * sm[bof2 + l]);
    a = __expf(dt * Ad[3]); H[3] = fmaf(a, H[3], dx * sm[bof3 + l]);
  }
  size_t base = (size_t)bc * 512 + (size_t)(d * 16 + s4);
  *reinterpret_cast<float4*>(Pb + base) =
      make_float4(__expf(sumdt * Ad[0]), __expf(sumdt * Ad[1]),
                  __expf(sumdt * Ad[2]), __expf(sumdt * Ad[3]));
  *reinterpret_cast<float4*>(Hb + base) = make_float4(H[0], H[1], H[2], H[3]);
}

// ---- K3: exclusive scan over chunks
__global__ __launch_bounds__(64) void k_combine(const float* __restrict__ Pb,
                                                const float* __restrict__ Hb,
                                                float* __restrict__ hs) {
  int g = blockIdx.x * 64 + threadIdx.x;
  int b = g >> 9, st = g & 511;
  size_t base = (size_t)b * NCH * 512 + st;
  float h = 0.f;
#pragma unroll 4
  for (int c = 0; c < NCH; c++) {
    size_t o = base + (size_t)c * 512;
    hs[o] = h;
    h = fmaf(Pb[o], h, Hb[o]);
  }
}

// ---- K4: per-chunk scan -> y comp-major [chunk][32][64]
__global__ __launch_bounds__(128) void k_scan(const float* __restrict__ rec,
                                              const float* __restrict__ A_log,
                                              const float* __restrict__ hs,
                                              float* __restrict__ yb) {
  __shared__ float sm[96 * 65];
  int t = threadIdx.x, bc = blockIdx.x;
  const float* cbase = rec + (size_t)bc * CHF;
#pragma unroll
  for (int i = 0; i < 12; i++) {
    int g4 = i * 512 + t * 4;
    int c = g4 >> 6, l = g4 & 63;
    *reinterpret_cast<float4*>(&sm[c * 65 + l]) =
        *reinterpret_cast<const float4*>(cbase + g4);
  }
  __syncthreads();
  int d = t >> 2, s4 = (t & 3) << 2;
  float4 al = *reinterpret_cast<const float4*>(A_log + d * DSTA + s4);
  float Ad[4] = {-__expf(al.x), -__expf(al.y), -__expf(al.z), -__expf(al.w)};
  float h[4];
  {
    float4 hv = *reinterpret_cast<const float4*>(hs + (size_t)bc * 512 +
                                                 (size_t)(d * 16 + s4));
    h[0] = hv.x; h[1] = hv.y; h[2] = hv.z; h[3] = hv.w;
  }
  int dof = d * 65, xof = (32 + d) * 65;
  int bof0 = (64 + s4) * 65, bof1 = (65 + s4) * 65, bof2 = (66 + s4) * 65,
      bof3 = (67 + s4) * 65;
  int cof0 = (80 + s4) * 65, cof1 = (81 + s4) * 65, cof2 = (82 + s4) * 65,
      cof3 = (83 + s4) * 65;
  bool wy = (t & 3) == 0;
#pragma unroll 2
  for (int l = 0; l < CL; l++) {
    float dt = sm[dof + l];
    float xcv = sm[xof + l];
    float dx = dt * xcv;
    float a;
    a = __expf(dt * Ad[0]); h[0] = fmaf(a, h[0], dx * sm[bof0 + l]);
    a = __expf(dt * Ad[1]); h[1] = fmaf(a, h[1], dx * sm[bof1 + l]);
    a = __expf(dt * Ad[2]); h[2] = fmaf(a, h[2], dx * sm[bof2 + l]);
    a = __expf(dt * Ad[3]); h[3] = fmaf(a, h[3], dx * sm[bof3 + l]);
    float y = sm[cof0 + l] * h[0];
    y = fmaf(sm[cof1 + l], h[1], y);
    y = fmaf(sm[cof2 + l], h[2], y);
    y = fmaf(sm[cof3 + l], h[3], y);
    y += __shfl_xor(y, 1);
    y += __shfl_xor(y, 2);
    // write y into the dead dt slot (wave-partitioned by d: no cross-wave race)
    if (wy) sm[dof + l] = y;
  }
  __syncthreads();
  float* ybase = yb + (size_t)bc * 2048;
#pragma unroll
  for (int i = 0; i < 16; i++) {
    int g = i * 128 + t;
    int d2 = g >> 6, l2 = g & 63;
    ybase[g] = sm[d2 * 65 + l2];
  }
}

// ---- K5: MFMA epilogue (unchanged from R4) ----
__device__ __forceinline__ bf16x8 afrag(const float* sb, int lrow, int kg,
                                        int kreal) {
  bf16x8 a = {0, 0, 0, 0, 0, 0, 0, 0};
  if (kg * 8 < kreal) {
    const float4* p = reinterpret_cast<const float4*>(sb + lrow * 36 + kg * 8);
    float4 u = p[0], v = p[1];
    a[0] = f2bf(u.x); a[1] = f2bf(u.y); a[2] = f2bf(u.z); a[3] = f2bf(u.w);
    a[4] = f2bf(v.x); a[5] = f2bf(v.y); a[6] = f2bf(v.z); a[7] = f2bf(v.w);
  }
  return a;
}

__global__ __launch_bounds__(256) void k_mlp(
    const float* __restrict__ rec, const float* __restrict__ yb,
    const float* __restrict__ x, const float* __restrict__ rms1w,
    const float* __restrict__ ipw, const float* __restrict__ Dskip,
    const float* __restrict__ opw, const float* __restrict__ rms2w,
    const float* __restrict__ f1w, const float* __restrict__ f1b,
    const float* __restrict__ f2w, const float* __restrict__ f2b,
    const float* __restrict__ f3w, const float* __restrict__ f3b,
    float* __restrict__ out) {
  __shared__ float sb[256 * 36];
  int t = threadIdx.x;
  int lane = t & 63, wid = t >> 6;
  int col = lane & 15, kg = lane >> 4;
  long rowbase = (long)blockIdx.x * 256;

  bf16x8 Bz0 = bfrag(ipw + 32, 64, 0, col, kg, 16);
  bf16x8 Bz1 = bfrag(ipw + 32, 64, 16, col, kg, 16);
  bf16x8 Bop = bfrag(opw, 16, 0, col, kg, 32);
  bf16x8 Bf1_0 = bfrag(f1w, 32, 0, col, kg, 16);
  bf16x8 Bf1_1 = bfrag(f1w, 32, 16, col, kg, 16);
  bf16x8 Bf2_0 = bfrag(f2w, 32, 0, col, kg, 32);
  bf16x8 Bf2_1 = bfrag(f2w, 32, 16, col, kg, 32);
  bf16x8 Bf3 = bfrag(f3w, 16, 0, col, kg, 32);
  float b1_0 = f1b[col], b1_1 = f1b[16 + col];
  float b2_0 = f2b[col], b2_1 = f2b[16 + col];
  float b3_c = f3b[col];
  float dsk0 = Dskip[col], dsk1 = Dskip[16 + col];
  float rw2 = rms2w[col];

  {
    float xr[16];
    load_x_row(x, rowbase + t, xr);
    float ss = 0.f;
#pragma unroll
    for (int i = 0; i < 16; i++) ss += xr[i] * xr[i];
    float inv1 = rsqrtf(ss * (1.f / 16.f) + 1e-6f);
#pragma unroll
    for (int i = 0; i < 16; i += 4) {
      float4 w = make_float4(xr[i] * inv1 * rms1w[i],
                             xr[i + 1] * inv1 * rms1w[i + 1],
                             xr[i + 2] * inv1 * rms1w[i + 2],
                             xr[i + 3] * inv1 * rms1w[i + 3]);
      *reinterpret_cast<float4*>(&sb[t * 36 + i]) = w;
    }
  }
  __syncthreads();

  int wr0 = wid * 64;
  int chunk = (int)(rowbase >> 6) + wid;
  const float* xcc = rec + (size_t)chunk * CHF + 32 * 64;
  const float* ybc = yb + (size_t)chunk * 2048;
  const f32x4 zero4 = {0.f, 0.f, 0.f, 0.f};
#pragma unroll 1
  for (int rt = 0; rt < 4; rt++) {
    int tile0 = wr0 + rt * 16;
    bf16x8 ax0 = afrag(sb, tile0 + col, kg, 16);
    f32x4 zf0 = mm(ax0, Bz0, zero4);
    f32x4 zf1 = mm(ax0, Bz1, zero4);
#pragma unroll
    for (int reg = 0; reg < 4; reg++) {
      int lrow = tile0 + kg * 4 + reg;
      int lloc = rt * 16 + kg * 4 + reg;
      float y0 = ybc[col * 64 + lloc];
      float y1 = ybc[(16 + col) * 64 + lloc];
      float xc0 = xcc[col * 64 + lloc];
      float xc1 = xcc[(16 + col) * 64 + lloc];
      float yo0 = (y0 + dsk0 * xc0) * fsilu(zf0[reg]);
      float yo1 = (y1 + dsk1 * xc1) * fsilu(zf1[reg]);
      sb[lrow * 36 + col] = yo0;
      sb[lrow * 36 + 16 + col] = yo1;
    }
    bf16x8 ayo = afrag(sb, tile0 + col, kg, 32);
    f32x4 x1f = mm(ayo, Bop, zero4);
    float xres[4];
#pragma unroll
    for (int reg = 0; reg < 4; reg++) {
      long grow = rowbase + tile0 + kg * 4 + reg;
      xres[reg] = x1f[reg] + x[grow * 16 + col];
    }
    float x2v[4];
#pragma unroll
    for (int reg = 0; reg < 4; reg++) {
      float ss = xres[reg] * xres[reg];
      ss += __shfl_xor(ss, 1);
      ss += __shfl_xor(ss, 2);
      ss += __shfl_xor(ss, 4);
      ss += __shfl_xor(ss, 8);
      float inv2 = rsqrtf(ss * (1.f / 16.f) + 1e-6f);
      x2v[reg] = xres[reg] * inv2 * rw2;
      sb[(tile0 + kg * 4 + reg) * 36 + col] = x2v[reg];
    }
    bf16x8 ax2 = afrag(sb, tile0 + col, kg, 16);
    f32x4 h1f0 = mm(ax2, Bf1_0, zero4);
    f32x4 h1f1 = mm(ax2, Bf1_1, zero4);
#pragma unroll
    for (int reg = 0; reg < 4; reg++) {
      int lrow = tile0 + kg * 4 + reg;
      sb[lrow * 36 + col] = fmaxf(h1f0[reg] + b1_0, 0.f);
      sb[lrow * 36 + 16 + col] = fmaxf(h1f1[reg] + b1_1, 0.f);
    }
    bf16x8 ah1 = afrag(sb, tile0 + col, kg, 32);
    f32x4 h2f0 = mm(ah1, Bf2_0, zero4);
    f32x4 h2f1 = mm(ah1, Bf2_1, zero4);
#pragma unroll
    for (int reg = 0; reg < 4; reg++) {
      int lrow = tile0 + kg * 4 + reg;
      sb[lrow * 36 + col] = fmaxf(h2f0[reg] + b2_0, 0.f);
      sb[lrow * 36 + 16 + col] = fmaxf(h2f1[reg] + b2_1, 0.f);
    }
    bf16x8 ah2 = afrag(sb, tile0 + col, kg, 32);
    f32x4 x3f = mm(ah2, Bf3, zero4);
#pragma unroll
    for (int reg = 0; reg < 4; reg++) {
      long grow = rowbase + tile0 + kg * 4 + reg;
      out[grow * 16 + col] = xres[reg] + x3f[reg] + b3_c;
    }
  }
}

extern "C" void kernel_launch(void* const* d_in, const int* in_sizes, int n_in,
                              void* d_out, int out_size, void* d_ws,
                              size_t ws_size, hipStream_t stream) {
  const float* x = (const float*)d_in[0];
  const float* rms1w = (const float*)d_in[1];
  const float* ipw = (const float*)d_in[2];
  const float* cw = (const float*)d_in[3];
  const float* cb = (const float*)d_in[4];
  const float* xpw = (const float*)d_in[5];
  const float* dtw = (const float*)d_in[6];
  const float* dtb = (const float*)d_in[7];
  const float* A_log = (const float*)d_in[8];
  const float* Dskip = (const float*)d_in[9];
  const float* opw = (const float*)d_in[10];
  const float* rms2w = (const float*)d_in[11];
  const float* f1w = (const float*)d_in[12];
  const float* f1b = (const float*)d_in[13];
  const float* f2w = (const float*)d_in[14];
  const float* f2b = (const float*)d_in[15];
  const float* f3w = (const float*)d_in[16];
  const float* f3b = (const float*)d_in[17];
  float* out = (float*)d_out;

  float* rec = (float*)d_ws;                  // 50.3 MiB
  float* Pb = rec + (size_t)NCHT * CHF;       // 4 MiB
  float* Hb = Pb + SUMN;                      // 4 MiB
  float* hsb = Hb + SUMN;                     // 4 MiB
  float* yb = hsb + SUMN;                     // 16.8 MiB

  hipLaunchKernelGGL(k_prep, dim3(NROWS / 256), dim3(256), 0, stream, x, rms1w,
                     ipw, cw, cb, xpw, dtw, dtb, rec);
  hipLaunchKernelGGL(k_chunk, dim3(NCHT), dim3(128), 0, stream, rec, A_log, Pb,
                     Hb);
  hipLaunchKernelGGL(k_combine, dim3((NBAT * 512) / 64), dim3(64), 0, stream,
                     Pb, Hb, hsb);
  hipLaunchKernelGGL(k_scan, dim3(NCHT), dim3(128), 0, stream, rec, A_log, hsb,
                     yb);
  hipLaunchKernelGGL(k_mlp, dim3(NROWS / 256), dim3(256), 0, stream, rec, yb, x,
                     rms1w, ipw, Dskip, opw, rms2w, f1w, f1b, f2w, f2b, f3w,
                     f3b, out);
}